// Round 1
// baseline (2572.295 us; speedup 1.0000x reference)
//
#include <hip/hip_runtime.h>
#include <math.h>

// ---------------------------------------------------------------------------
// DCN_Align pipeline on MI355X, fp32 direct convolutions.
// Each conv thread: 1 output pixel, 32 (or 36) output-channel accumulators in
// VGPRs; weights read via wave-uniform addresses -> scalar loads (SGPR operand
// of v_fmac_f32). Concats fused via dual input pointers.
// ---------------------------------------------------------------------------

#define BDIM 256

template<int C0, int C1, int COUTC, int STRIDE, bool LRELU>
__global__ __launch_bounds__(BDIM)
void conv3x3_k(const float* __restrict__ in0, const float* __restrict__ in1,
               const float* __restrict__ w, const float* __restrict__ bias,
               float* __restrict__ out,
               int Hin, int Win, int Hout, int Wout,
               int coutTotal, int nChunk)
{
    constexpr int CIN = C0 + C1;
    const int bz = blockIdx.z;
    const int b = bz / nChunk;
    const int chunk = bz - b * nChunk;
    const int cout_base = chunk * COUTC;

    const int ox = blockIdx.x * 16 + (threadIdx.x & 15);
    const int oy = blockIdx.y * 16 + (threadIdx.x >> 4);
    if (ox >= Wout || oy >= Hout) return;

    const int iy0 = oy * STRIDE - 1;
    const int ix0 = ox * STRIDE - 1;

    float acc[COUTC];
#pragma unroll
    for (int o = 0; o < COUTC; ++o) acc[o] = bias[cout_base + o];

    // ---- channels from in0 ----
    {
        const float* base = in0 + (size_t)b * C0 * Hin * Win;
        for (int c = 0; c < C0; ++c) {
            const float* img = base + (size_t)c * Hin * Win;
            float v[9];
#pragma unroll
            for (int t = 0; t < 9; ++t) {
                const int yy = iy0 + t / 3;
                const int xx = ix0 + t % 3;
                const bool ok = ((unsigned)yy < (unsigned)Hin) && ((unsigned)xx < (unsigned)Win);
                v[t] = ok ? img[yy * Win + xx] : 0.f;
            }
            const float* wp = w + ((size_t)cout_base * CIN + c) * 9;
#pragma unroll
            for (int o = 0; o < COUTC; ++o) {
#pragma unroll
                for (int t = 0; t < 9; ++t)
                    acc[o] = fmaf(v[t], wp[(size_t)o * CIN * 9 + t], acc[o]);
            }
        }
    }
    // ---- channels from in1 (fused concat) ----
    if (C1 > 0) {
        const float* base = in1 + (size_t)b * C1 * Hin * Win;
        for (int c = 0; c < C1; ++c) {
            const float* img = base + (size_t)c * Hin * Win;
            float v[9];
#pragma unroll
            for (int t = 0; t < 9; ++t) {
                const int yy = iy0 + t / 3;
                const int xx = ix0 + t % 3;
                const bool ok = ((unsigned)yy < (unsigned)Hin) && ((unsigned)xx < (unsigned)Win);
                v[t] = ok ? img[yy * Win + xx] : 0.f;
            }
            const float* wp = w + ((size_t)cout_base * CIN + (C0 + c)) * 9;
#pragma unroll
            for (int o = 0; o < COUTC; ++o) {
#pragma unroll
                for (int t = 0; t < 9; ++t)
                    acc[o] = fmaf(v[t], wp[(size_t)o * CIN * 9 + t], acc[o]);
            }
        }
    }

    float* op = out + ((size_t)b * coutTotal + cout_base) * Hout * Wout
                    + (size_t)oy * Wout + ox;
#pragma unroll
    for (int o = 0; o < COUTC; ++o) {
        float r = acc[o];
        if (LRELU) r = (r >= 0.f) ? r : 0.1f * r;
        op[(size_t)o * Hout * Wout] = r;
    }
}

// Bilinear 2x upsample, half-pixel centers, edge clamp (== jax.image.resize
// 'bilinear' after its boundary weight renormalization).
__global__ __launch_bounds__(BDIM)
void up2_k(const float* __restrict__ in, float* __restrict__ out,
           int C /* = B*C planes */, int Hin, int Win)
{
    const int Hout = Hin * 2, Wout = Win * 2;
    const int idx = blockIdx.x * BDIM + threadIdx.x;
    const int total = C * Hout * Wout;
    if (idx >= total) return;
    const int x = idx % Wout;
    int t = idx / Wout;
    const int y = t % Hout;
    const int c = t / Hout;

    const float sy = (y + 0.5f) * 0.5f - 0.5f;
    const float sx = (x + 0.5f) * 0.5f - 0.5f;
    const float y0f = floorf(sy), x0f = floorf(sx);
    const float wy = sy - y0f, wx = sx - x0f;
    const int y0 = (int)y0f, x0 = (int)x0f;
    const int y0c = min(max(y0, 0), Hin - 1);
    const int y1c = min(max(y0 + 1, 0), Hin - 1);
    const int x0c = min(max(x0, 0), Win - 1);
    const int x1c = min(max(x0 + 1, 0), Win - 1);
    const float* img = in + (size_t)c * Hin * Win;
    const float v00 = img[y0c * Win + x0c];
    const float v01 = img[y0c * Win + x1c];
    const float v10 = img[y1c * Win + x0c];
    const float v11 = img[y1c * Win + x1c];
    out[idx] = (1.f - wy) * ((1.f - wx) * v00 + wx * v01)
             + wy * ((1.f - wx) * v10 + wx * v11);
}

// Modulated deformable conv (DCNv2), 3x3, pad 1, stride 1, DG=4 groups.
__global__ __launch_bounds__(BDIM)
void dcn_k(const float* __restrict__ x, const float* __restrict__ om,
           const float* __restrict__ w, const float* __restrict__ bias,
           float* __restrict__ out, int H, int W)
{
    const int idx = blockIdx.x * BDIM + threadIdx.x;
    const int total = 4 * H * W;
    if (idx >= total) return;
    const int xo = idx % W;
    int t = idx / W;
    const int yo = t % H;
    const int b = t / H;

    const size_t plane = (size_t)H * W;

    float acc[32];
#pragma unroll
    for (int o = 0; o < 32; ++o) acc[o] = bias[o];

    const float* omb = om + (size_t)b * 108 * plane + (size_t)yo * W + xo;

    for (int g = 0; g < 4; ++g) {
#pragma unroll
        for (int k = 0; k < 9; ++k) {
            const float offy = omb[(size_t)(g * 9 + k) * plane];
            const float offx = omb[(size_t)(36 + g * 9 + k) * plane];
            const float ml   = omb[(size_t)(72 + g * 9 + k) * plane];
            const float m = 1.f / (1.f + __expf(-ml));

            const float py = offy + (float)yo + (float)(k / 3 - 1);
            const float px = offx + (float)xo + (float)(k % 3 - 1);
            const float y0f = floorf(py), x0f = floorf(px);
            const int y0 = (int)y0f, x0 = (int)x0f;
            const float wy1 = py - y0f, wx1 = px - x0f;
            const float wy0 = 1.f - wy1, wx0 = 1.f - wx1;

            const bool y0ok = (unsigned)y0 < (unsigned)H;
            const bool y1ok = (unsigned)(y0 + 1) < (unsigned)H;
            const bool x0ok = (unsigned)x0 < (unsigned)W;
            const bool x1ok = (unsigned)(x0 + 1) < (unsigned)W;
            const int y0c = min(max(y0, 0), H - 1);
            const int y1c = min(max(y0 + 1, 0), H - 1);
            const int x0c = min(max(x0, 0), W - 1);
            const int x1c = min(max(x0 + 1, 0), W - 1);

            const float w00 = wy0 * wx0 * ((y0ok && x0ok) ? 1.f : 0.f) * m;
            const float w01 = wy0 * wx1 * ((y0ok && x1ok) ? 1.f : 0.f) * m;
            const float w10 = wy1 * wx0 * ((y1ok && x0ok) ? 1.f : 0.f) * m;
            const float w11 = wy1 * wx1 * ((y1ok && x1ok) ? 1.f : 0.f) * m;

            const int i00 = y0c * W + x0c, i01 = y0c * W + x1c;
            const int i10 = y1c * W + x0c, i11 = y1c * W + x1c;

            const float* imgb = x + ((size_t)b * 32 + g * 8) * plane;
#pragma unroll
            for (int c = 0; c < 8; ++c) {
                const float* img = imgb + (size_t)c * plane;
                const float s = w00 * img[i00] + w01 * img[i01]
                              + w10 * img[i10] + w11 * img[i11];
                // w layout: [O=32][I=32][3][3]; input channel = g*8+c, tap k
                const float* wp = w + ((size_t)(g * 8 + c)) * 9 + k;
#pragma unroll
                for (int o = 0; o < 32; ++o)
                    acc[o] = fmaf(s, wp[(size_t)o * 32 * 9], acc[o]);
            }
        }
    }

    float* op = out + (size_t)b * 32 * plane + (size_t)yo * W + xo;
#pragma unroll
    for (int o = 0; o < 32; ++o) op[(size_t)o * plane] = acc[o];
}

// ---------------------------------------------------------------------------

extern "C" void kernel_launch(void* const* d_in, const int* in_sizes, int n_in,
                              void* d_out, int out_size, void* d_ws, size_t ws_size,
                              hipStream_t stream)
{
    const float* fea1  = (const float*)d_in[0];
    const float* fea2  = (const float*)d_in[1];
    const float* w1_1  = (const float*)d_in[2];  const float* b1_1 = (const float*)d_in[3];
    const float* w2_1  = (const float*)d_in[4];  const float* b2_1 = (const float*)d_in[5];
    const float* w3_1  = (const float*)d_in[6];  const float* b3_1 = (const float*)d_in[7];
    const float* w4_1  = (const float*)d_in[8];  const float* b4_1 = (const float*)d_in[9];
    const float* w6_1  = (const float*)d_in[10]; const float* b6_1 = (const float*)d_in[11];
    const float* w7_1  = (const float*)d_in[12]; const float* b7_1 = (const float*)d_in[13];
    const float* w1_2  = (const float*)d_in[14]; const float* b1_2 = (const float*)d_in[15];
    const float* w2_2  = (const float*)d_in[16]; const float* b2_2 = (const float*)d_in[17];
    const float* w3_2  = (const float*)d_in[18]; const float* b3_2 = (const float*)d_in[19];
    const float* w4_2  = (const float*)d_in[20]; const float* b4_2 = (const float*)d_in[21];
    const float* w_om  = (const float*)d_in[22]; const float* b_om = (const float*)d_in[23];
    const float* w_dcn = (const float*)d_in[24]; const float* b_dcn= (const float*)d_in[25];

    const int B = 4, H = 192, W = 192;
    const size_t sz192 = (size_t)B * 32 * H * W * 4;          // 18,874,368
    const size_t sz96  = (size_t)B * 32 * (H/2) * (W/2) * 4;  //  4,718,592
    const size_t sz48  = (size_t)B * 32 * (H/4) * (W/4) * 4;  //  1,179,648

    char* ws = (char*)d_ws;
    float* bufA = (float*)(ws + 0);                         // off     @192
    float* bufB = (float*)(ws + sz192);                     // off1    @192 (long-lived)
    float* bufC = (float*)(ws + 2 * sz192);                 // off2a   @96
    float* bufD = (float*)(ws + 2 * sz192 + sz96);          // off2    @96 (lives to conv1_2)
    float* bufE = (float*)(ws + 2 * sz192 + 2 * sz96);      // off3a   @48
    float* bufF = (float*)(ws + 2 * sz192 + 2 * sz96 + sz48);        // off3 @48
    float* bufG = (float*)(ws + 2 * sz192 + 2 * sz96 + 2 * sz48);    // up96
    float* bufH = (float*)(ws + 0);                         // reuse A slot @96
    float* bufI = (float*)(ws + 2 * sz192);                 // reuse C slot @96
    float* bufJ = (float*)(ws + 0);                         // up192, reuse (H dead)
    float* bufK = (float*)(ws + 2 * sz192 + 3 * sz96 + 2 * sz48);    // conv3_2 out @192
    float* bufL = (float*)(ws + 0);                         // base_offset @192 (J,B dead)
    float* bufM = (float*)(ws + sz192);                     // om (108ch) 63.7 MB

    dim3 blk(BDIM, 1, 1);
    dim3 g192((W + 15) / 16, (H + 15) / 16, B);
    dim3 g96((W/2 + 15) / 16, (H/2 + 15) / 16, B);
    dim3 g48((W/4 + 15) / 16, (H/4 + 15) / 16, B);

    // 1. off = lrelu(conv1_1(cat(fea1, fea2)))          192
    conv3x3_k<32, 32, 32, 1, true><<<g192, blk, 0, stream>>>(
        fea1, fea2, w1_1, b1_1, bufA, H, W, H, W, 32, 1);
    // 2. off1 = lrelu(conv2_1(off))                     192
    conv3x3_k<32, 0, 32, 1, true><<<g192, blk, 0, stream>>>(
        bufA, nullptr, w2_1, b2_1, bufB, H, W, H, W, 32, 1);
    // 3. off2a = lrelu(conv3_1(off1, s2))               96
    conv3x3_k<32, 0, 32, 2, true><<<g96, blk, 0, stream>>>(
        bufB, nullptr, w3_1, b3_1, bufC, H, W, H/2, W/2, 32, 1);
    // 4. off2 = lrelu(conv4_1(off2a))                   96
    conv3x3_k<32, 0, 32, 1, true><<<g96, blk, 0, stream>>>(
        bufC, nullptr, w4_1, b4_1, bufD, H/2, W/2, H/2, W/2, 32, 1);
    // 5. off3a = lrelu(conv6_1(off2, s2))               48
    conv3x3_k<32, 0, 32, 2, true><<<g48, blk, 0, stream>>>(
        bufD, nullptr, w6_1, b6_1, bufE, H/2, W/2, H/4, W/4, 32, 1);
    // 6. off3 = lrelu(conv7_1(off3a))                   48
    conv3x3_k<32, 0, 32, 1, true><<<g48, blk, 0, stream>>>(
        bufE, nullptr, w7_1, b7_1, bufF, H/4, W/4, H/4, W/4, 32, 1);
    // 7. up96 = up2(off3)                               48 -> 96
    {
        int total = B * 32 * (H/2) * (W/2);
        up2_k<<<dim3((total + BDIM - 1) / BDIM), blk, 0, stream>>>(
            bufF, bufG, B * 32, H/4, W/4);
    }
    // 8. t = lrelu(conv1_2(cat(up96, off2)))            96
    conv3x3_k<32, 32, 32, 1, true><<<g96, blk, 0, stream>>>(
        bufG, bufD, w1_2, b1_2, bufH, H/2, W/2, H/2, W/2, 32, 1);
    // 9. t2 = lrelu(conv2_2(t))                         96
    conv3x3_k<32, 0, 32, 1, true><<<g96, blk, 0, stream>>>(
        bufH, nullptr, w2_2, b2_2, bufI, H/2, W/2, H/2, W/2, 32, 1);
    // 10. up192 = up2(t2)                               96 -> 192
    {
        int total = B * 32 * H * W;
        up2_k<<<dim3((total + BDIM - 1) / BDIM), blk, 0, stream>>>(
            bufI, bufJ, B * 32, H/2, W/2);
    }
    // 11. off = lrelu(conv3_2(cat(up192, off1)))        192
    conv3x3_k<32, 32, 32, 1, true><<<g192, blk, 0, stream>>>(
        bufJ, bufB, w3_2, b3_2, bufK, H, W, H, W, 32, 1);
    // 12. base_offset = conv4_2(off)                    192 (no lrelu)
    conv3x3_k<32, 0, 32, 1, false><<<g192, blk, 0, stream>>>(
        bufK, nullptr, w4_2, b4_2, bufL, H, W, H, W, 32, 1);
    // 13. om = conv_om(base_offset)   32 -> 108         192 (no lrelu)
    {
        dim3 gom((W + 15) / 16, (H + 15) / 16, B * 3);
        conv3x3_k<32, 0, 36, 1, false><<<gom, blk, 0, stream>>>(
            bufL, nullptr, w_om, b_om, bufM, H, W, H, W, 108, 3);
    }
    // 14. out = deform_conv(fea2, om)
    {
        int total = B * H * W;
        dcn_k<<<dim3((total + BDIM - 1) / BDIM), blk, 0, stream>>>(
            fea2, bufM, w_dcn, b_dcn, (float*)d_out, H, W);
    }
}

// Round 2
// 1039.261 us; speedup vs baseline: 2.4751x; 2.4751x over previous
//
#include <hip/hip_runtime.h>
#include <math.h>

// ---------------------------------------------------------------------------
// DCN_Align pipeline on MI355X, fp32 direct convolutions.
// Conv: 1 thread = 1 output pixel x 16 output channels (weights via scalar
// loads). DCN: 4 waves/block, one deformable group per wave, NHWC-transposed
// input for contiguous channel loads, LDS reduction across groups.
// ---------------------------------------------------------------------------

#define BDIM 256

template<int C0, int C1, int COUTC, int STRIDE, bool LRELU>
__global__ __launch_bounds__(BDIM)
void conv3x3_k(const float* __restrict__ in0, const float* __restrict__ in1,
               const float* __restrict__ w, const float* __restrict__ bias,
               float* __restrict__ out,
               int Hin, int Win, int Hout, int Wout,
               int coutTotal, int nChunk)
{
    constexpr int CIN = C0 + C1;
    const int bz = blockIdx.z;
    const int b = bz / nChunk;
    const int chunk = bz - b * nChunk;
    const int cout_base = chunk * COUTC;

    const int ox = blockIdx.x * 16 + (threadIdx.x & 15);
    const int oy = blockIdx.y * 16 + (threadIdx.x >> 4);
    if (ox >= Wout || oy >= Hout) return;

    const int iy0 = oy * STRIDE - 1;
    const int ix0 = ox * STRIDE - 1;

    float acc[COUTC];
#pragma unroll
    for (int o = 0; o < COUTC; ++o) acc[o] = bias[cout_base + o];

    // ---- channels from in0 ----
    {
        const float* base = in0 + (size_t)b * C0 * Hin * Win;
        for (int c = 0; c < C0; ++c) {
            const float* img = base + (size_t)c * Hin * Win;
            float v[9];
#pragma unroll
            for (int t = 0; t < 9; ++t) {
                const int yy = iy0 + t / 3;
                const int xx = ix0 + t % 3;
                const bool ok = ((unsigned)yy < (unsigned)Hin) && ((unsigned)xx < (unsigned)Win);
                v[t] = ok ? img[yy * Win + xx] : 0.f;
            }
            const float* wp = w + ((size_t)cout_base * CIN + c) * 9;
#pragma unroll
            for (int o = 0; o < COUTC; ++o) {
#pragma unroll
                for (int t = 0; t < 9; ++t)
                    acc[o] = fmaf(v[t], wp[(size_t)o * CIN * 9 + t], acc[o]);
            }
        }
    }
    // ---- channels from in1 (fused concat) ----
    if (C1 > 0) {
        const float* base = in1 + (size_t)b * C1 * Hin * Win;
        for (int c = 0; c < C1; ++c) {
            const float* img = base + (size_t)c * Hin * Win;
            float v[9];
#pragma unroll
            for (int t = 0; t < 9; ++t) {
                const int yy = iy0 + t / 3;
                const int xx = ix0 + t % 3;
                const bool ok = ((unsigned)yy < (unsigned)Hin) && ((unsigned)xx < (unsigned)Win);
                v[t] = ok ? img[yy * Win + xx] : 0.f;
            }
            const float* wp = w + ((size_t)cout_base * CIN + (C0 + c)) * 9;
#pragma unroll
            for (int o = 0; o < COUTC; ++o) {
#pragma unroll
                for (int t = 0; t < 9; ++t)
                    acc[o] = fmaf(v[t], wp[(size_t)o * CIN * 9 + t], acc[o]);
            }
        }
    }

    float* op = out + ((size_t)b * coutTotal + cout_base) * Hout * Wout
                    + (size_t)oy * Wout + ox;
#pragma unroll
    for (int o = 0; o < COUTC; ++o) {
        float r = acc[o];
        if (LRELU) r = (r >= 0.f) ? r : 0.1f * r;
        op[(size_t)o * Hout * Wout] = r;
    }
}

// Bilinear 2x upsample, half-pixel centers, edge clamp.
__global__ __launch_bounds__(BDIM)
void up2_k(const float* __restrict__ in, float* __restrict__ out,
           int C, int Hin, int Win)
{
    const int Hout = Hin * 2, Wout = Win * 2;
    const int idx = blockIdx.x * BDIM + threadIdx.x;
    const int total = C * Hout * Wout;
    if (idx >= total) return;
    const int x = idx % Wout;
    int t = idx / Wout;
    const int y = t % Hout;
    const int c = t / Hout;

    const float sy = (y + 0.5f) * 0.5f - 0.5f;
    const float sx = (x + 0.5f) * 0.5f - 0.5f;
    const float y0f = floorf(sy), x0f = floorf(sx);
    const float wy = sy - y0f, wx = sx - x0f;
    const int y0 = (int)y0f, x0 = (int)x0f;
    const int y0c = min(max(y0, 0), Hin - 1);
    const int y1c = min(max(y0 + 1, 0), Hin - 1);
    const int x0c = min(max(x0, 0), Win - 1);
    const int x1c = min(max(x0 + 1, 0), Win - 1);
    const float* img = in + (size_t)c * Hin * Win;
    const float v00 = img[y0c * Win + x0c];
    const float v01 = img[y0c * Win + x1c];
    const float v10 = img[y1c * Win + x0c];
    const float v11 = img[y1c * Win + x1c];
    out[idx] = (1.f - wy) * ((1.f - wx) * v00 + wx * v01)
             + wy * ((1.f - wx) * v10 + wx * v11);
}

// NCHW [4][32][192][192] -> NHWC [4][192][192][32]
__global__ __launch_bounds__(BDIM)
void nhwc_k(const float* __restrict__ in, float* __restrict__ out, int H, int W)
{
    const int idx = blockIdx.x * BDIM + threadIdx.x;
    if (idx >= 4 * 32 * H * W) return;
    const int c = idx & 31;
    int t = idx >> 5;
    const int x = t % W; t /= W;
    const int y = t % H;
    const int b = t / H;
    out[idx] = in[(((size_t)b * 32 + c) * H + y) * W + x];
}

// w_dcn [32o][32i][9k] -> wt [9k][32i][32o]
__global__ __launch_bounds__(BDIM)
void wtr_k(const float* __restrict__ in, float* __restrict__ out)
{
    const int idx = blockIdx.x * BDIM + threadIdx.x;
    if (idx >= 9 * 32 * 32) return;
    const int o = idx & 31;
    const int i = (idx >> 5) & 31;
    const int k = idx >> 10;
    out[idx] = in[((size_t)o * 32 + i) * 9 + k];
}

// Modulated deformable conv (DCNv2), 3x3, pad 1, stride 1, DG=4 groups.
// Block = 256 threads = 4 waves; wave g handles group g for 64 consecutive
// x-pixels. LDS reduction across groups.
__global__ __launch_bounds__(BDIM)
void dcn_k(const float* __restrict__ xt,   // NHWC [B][H][W][32]
           const float* __restrict__ om,   // planar [B][108][H][W]
           const float* __restrict__ wt,   // [9][32][32] (k, cin, cout)
           const float* __restrict__ bias,
           float* __restrict__ out, int H, int W)
{
    const int lane = threadIdx.x & 63;
    const int gu = __builtin_amdgcn_readfirstlane(threadIdx.x >> 6);
    const int P = blockIdx.x * 64;
    const int b = P / (H * W);
    int p = P - b * H * W;
    const int y = p / W;
    const int x = (p - y * W) + lane;
    const size_t plane = (size_t)H * W;

    __shared__ float red[4][64][33];

    float acc[32];
#pragma unroll
    for (int o = 0; o < 32; ++o) acc[o] = 0.f;

    const float* omb = om + ((size_t)b * 108 + gu * 9) * plane + (size_t)y * W + x;
    const float* xb  = xt + (size_t)b * plane * 32 + gu * 8;

#pragma unroll
    for (int k = 0; k < 9; ++k) {
        const float offy = omb[(size_t)k * plane];
        const float offx = omb[(size_t)(36 + k) * plane];
        const float ml   = omb[(size_t)(72 + k) * plane];
        const float m = 1.f / (1.f + __expf(-ml));

        const float py = offy + (float)y + (float)(k / 3 - 1);
        const float px = offx + (float)x + (float)(k % 3 - 1);
        const float y0f = floorf(py), x0f = floorf(px);
        const int y0 = (int)y0f, x0 = (int)x0f;
        const float wy1 = py - y0f, wx1 = px - x0f;
        const float wy0 = 1.f - wy1, wx0 = 1.f - wx1;

        const bool y0ok = (unsigned)y0 < (unsigned)H;
        const bool y1ok = (unsigned)(y0 + 1) < (unsigned)H;
        const bool x0ok = (unsigned)x0 < (unsigned)W;
        const bool x1ok = (unsigned)(x0 + 1) < (unsigned)W;
        const int y0c = min(max(y0, 0), H - 1);
        const int y1c = min(max(y0 + 1, 0), H - 1);
        const int x0c = min(max(x0, 0), W - 1);
        const int x1c = min(max(x0 + 1, 0), W - 1);

        const float w00 = wy0 * wx0 * ((y0ok && x0ok) ? 1.f : 0.f) * m;
        const float w01 = wy0 * wx1 * ((y0ok && x1ok) ? 1.f : 0.f) * m;
        const float w10 = wy1 * wx0 * ((y1ok && x0ok) ? 1.f : 0.f) * m;
        const float w11 = wy1 * wx1 * ((y1ok && x1ok) ? 1.f : 0.f) * m;

        const float* c00 = xb + ((size_t)y0c * W + x0c) * 32;
        const float* c01 = xb + ((size_t)y0c * W + x1c) * 32;
        const float* c10 = xb + ((size_t)y1c * W + x0c) * 32;
        const float* c11 = xb + ((size_t)y1c * W + x1c) * 32;

        float4 a00 = *(const float4*)(c00), b00 = *(const float4*)(c00 + 4);
        float4 a01 = *(const float4*)(c01), b01 = *(const float4*)(c01 + 4);
        float4 a10 = *(const float4*)(c10), b10 = *(const float4*)(c10 + 4);
        float4 a11 = *(const float4*)(c11), b11 = *(const float4*)(c11 + 4);

        float s[8];
        s[0] = w00 * a00.x + w01 * a01.x + w10 * a10.x + w11 * a11.x;
        s[1] = w00 * a00.y + w01 * a01.y + w10 * a10.y + w11 * a11.y;
        s[2] = w00 * a00.z + w01 * a01.z + w10 * a10.z + w11 * a11.z;
        s[3] = w00 * a00.w + w01 * a01.w + w10 * a10.w + w11 * a11.w;
        s[4] = w00 * b00.x + w01 * b01.x + w10 * b10.x + w11 * b11.x;
        s[5] = w00 * b00.y + w01 * b01.y + w10 * b10.y + w11 * b11.y;
        s[6] = w00 * b00.z + w01 * b01.z + w10 * b10.z + w11 * b11.z;
        s[7] = w00 * b00.w + w01 * b01.w + w10 * b10.w + w11 * b11.w;

        const float* wk = wt + ((size_t)k * 32 + gu * 8) * 32;
#pragma unroll
        for (int c = 0; c < 8; ++c) {
#pragma unroll
            for (int o = 0; o < 32; ++o)
                acc[o] = fmaf(s[c], wk[c * 32 + o], acc[o]);
        }
    }

#pragma unroll
    for (int o = 0; o < 32; ++o) red[gu][lane][o] = acc[o];
    __syncthreads();

    float* op = out + (size_t)b * 32 * plane + (size_t)y * W + x;
#pragma unroll
    for (int j = 0; j < 8; ++j) {
        const int o = gu * 8 + j;
        float r = bias[o] + red[0][lane][o] + red[1][lane][o]
                          + red[2][lane][o] + red[3][lane][o];
        op[(size_t)o * plane] = r;
    }
}

// ---------------------------------------------------------------------------

extern "C" void kernel_launch(void* const* d_in, const int* in_sizes, int n_in,
                              void* d_out, int out_size, void* d_ws, size_t ws_size,
                              hipStream_t stream)
{
    const float* fea1  = (const float*)d_in[0];
    const float* fea2  = (const float*)d_in[1];
    const float* w1_1  = (const float*)d_in[2];  const float* b1_1 = (const float*)d_in[3];
    const float* w2_1  = (const float*)d_in[4];  const float* b2_1 = (const float*)d_in[5];
    const float* w3_1  = (const float*)d_in[6];  const float* b3_1 = (const float*)d_in[7];
    const float* w4_1  = (const float*)d_in[8];  const float* b4_1 = (const float*)d_in[9];
    const float* w6_1  = (const float*)d_in[10]; const float* b6_1 = (const float*)d_in[11];
    const float* w7_1  = (const float*)d_in[12]; const float* b7_1 = (const float*)d_in[13];
    const float* w1_2  = (const float*)d_in[14]; const float* b1_2 = (const float*)d_in[15];
    const float* w2_2  = (const float*)d_in[16]; const float* b2_2 = (const float*)d_in[17];
    const float* w3_2  = (const float*)d_in[18]; const float* b3_2 = (const float*)d_in[19];
    const float* w4_2  = (const float*)d_in[20]; const float* b4_2 = (const float*)d_in[21];
    const float* w_om  = (const float*)d_in[22]; const float* b_om = (const float*)d_in[23];
    const float* w_dcn = (const float*)d_in[24]; const float* b_dcn= (const float*)d_in[25];

    const int B = 4, H = 192, W = 192;
    const size_t sz192 = (size_t)B * 32 * H * W * 4;          // 18,874,368
    const size_t sz96  = (size_t)B * 32 * (H/2) * (W/2) * 4;
    const size_t sz48  = (size_t)B * 32 * (H/4) * (W/4) * 4;
    const size_t szOM  = (size_t)B * 108 * H * W * 4;         // 63,700,992

    char* ws = (char*)d_ws;
    float* bufA = (float*)(ws + 0);                         // off     @192
    float* bufB = (float*)(ws + sz192);                     // off1    @192
    float* bufC = (float*)(ws + 2 * sz192);                 // off2a   @96
    float* bufD = (float*)(ws + 2 * sz192 + sz96);          // off2    @96
    float* bufE = (float*)(ws + 2 * sz192 + 2 * sz96);      // off3a   @48
    float* bufF = (float*)(ws + 2 * sz192 + 2 * sz96 + sz48);        // off3 @48
    float* bufG = (float*)(ws + 2 * sz192 + 2 * sz96 + 2 * sz48);    // up96
    float* bufH = (float*)(ws + 0);                         // conv1_2 out @96
    float* bufI = (float*)(ws + 2 * sz192);                 // conv2_2 out @96
    float* bufJ = (float*)(ws + 0);                         // up192
    float* bufK = (float*)(ws + 2 * sz192 + 3 * sz96 + 2 * sz48);    // conv3_2 out @192
    float* bufL = (float*)(ws + 0);                         // base_offset @192
    float* bufM = (float*)(ws + sz192);                     // om (108ch planar)
    float* fea2t= (float*)(ws + 0);                         // NHWC fea2 (after bufL dead)
    float* wtb  = (float*)(ws + sz192 + szOM);              // 36 KB, past om

    dim3 blk(BDIM, 1, 1);
    dim3 g192((W + 15) / 16, (H + 15) / 16, B * 2);
    dim3 g96((W/2 + 15) / 16, (H/2 + 15) / 16, B * 2);
    dim3 g48((W/4 + 15) / 16, (H/4 + 15) / 16, B * 2);

    // 1. off = lrelu(conv1_1(cat(fea1, fea2)))
    conv3x3_k<32, 32, 16, 1, true><<<g192, blk, 0, stream>>>(
        fea1, fea2, w1_1, b1_1, bufA, H, W, H, W, 32, 2);
    // 2. off1 = lrelu(conv2_1(off))
    conv3x3_k<32, 0, 16, 1, true><<<g192, blk, 0, stream>>>(
        bufA, nullptr, w2_1, b2_1, bufB, H, W, H, W, 32, 2);
    // 3. off2a = lrelu(conv3_1(off1, s2))
    conv3x3_k<32, 0, 16, 2, true><<<g96, blk, 0, stream>>>(
        bufB, nullptr, w3_1, b3_1, bufC, H, W, H/2, W/2, 32, 2);
    // 4. off2 = lrelu(conv4_1(off2a))
    conv3x3_k<32, 0, 16, 1, true><<<g96, blk, 0, stream>>>(
        bufC, nullptr, w4_1, b4_1, bufD, H/2, W/2, H/2, W/2, 32, 2);
    // 5. off3a = lrelu(conv6_1(off2, s2))
    conv3x3_k<32, 0, 16, 2, true><<<g48, blk, 0, stream>>>(
        bufD, nullptr, w6_1, b6_1, bufE, H/2, W/2, H/4, W/4, 32, 2);
    // 6. off3 = lrelu(conv7_1(off3a))
    conv3x3_k<32, 0, 16, 1, true><<<g48, blk, 0, stream>>>(
        bufE, nullptr, w7_1, b7_1, bufF, H/4, W/4, H/4, W/4, 32, 2);
    // 7. up96 = up2(off3)
    {
        int total = B * 32 * (H/2) * (W/2);
        up2_k<<<dim3((total + BDIM - 1) / BDIM), blk, 0, stream>>>(
            bufF, bufG, B * 32, H/4, W/4);
    }
    // 8. t = lrelu(conv1_2(cat(up96, off2)))
    conv3x3_k<32, 32, 16, 1, true><<<g96, blk, 0, stream>>>(
        bufG, bufD, w1_2, b1_2, bufH, H/2, W/2, H/2, W/2, 32, 2);
    // 9. t2 = lrelu(conv2_2(t))
    conv3x3_k<32, 0, 16, 1, true><<<g96, blk, 0, stream>>>(
        bufH, nullptr, w2_2, b2_2, bufI, H/2, W/2, H/2, W/2, 32, 2);
    // 10. up192 = up2(t2)
    {
        int total = B * 32 * H * W;
        up2_k<<<dim3((total + BDIM - 1) / BDIM), blk, 0, stream>>>(
            bufI, bufJ, B * 32, H/2, W/2);
    }
    // 11. off = lrelu(conv3_2(cat(up192, off1)))
    conv3x3_k<32, 32, 16, 1, true><<<g192, blk, 0, stream>>>(
        bufJ, bufB, w3_2, b3_2, bufK, H, W, H, W, 32, 2);
    // 12. base_offset = conv4_2(off)   (no lrelu)
    conv3x3_k<32, 0, 16, 1, false><<<g192, blk, 0, stream>>>(
        bufK, nullptr, w4_2, b4_2, bufL, H, W, H, W, 32, 2);
    // 13. om = conv_om(base_offset)  32 -> 108  (no lrelu)
    {
        dim3 gom((W + 15) / 16, (H + 15) / 16, B * 6);
        conv3x3_k<32, 0, 18, 1, false><<<gom, blk, 0, stream>>>(
            bufL, nullptr, w_om, b_om, bufM, H, W, H, W, 108, 6);
    }
    // 13b. fea2 -> NHWC (bufL slot is dead now); w_dcn -> [k][i][o]
    {
        int total = B * 32 * H * W;
        nhwc_k<<<dim3((total + BDIM - 1) / BDIM), blk, 0, stream>>>(fea2, fea2t, H, W);
        wtr_k<<<dim3(36), blk, 0, stream>>>(w_dcn, wtb);
    }
    // 14. out = deform_conv(fea2, om)
    {
        int nblocks = B * H * W / 64;
        dcn_k<<<dim3(nblocks), blk, 0, stream>>>(
            fea2t, bufM, wtb, b_dcn, (float*)d_out, H, W);
    }
}

// Round 3
// 768.678 us; speedup vs baseline: 3.3464x; 1.3520x over previous
//
#include <hip/hip_runtime.h>
#include <math.h>

// ---------------------------------------------------------------------------
// DCN_Align pipeline on MI355X, fp32 direct convolutions.
// Conv: 1 thread = 1 output pixel x COUTC output channels. Taps double-
// buffered across the input-channel loop; bounds predication hoisted into
// precomputed clamped offsets + 0/1 masks; weights pre-transposed to
// [chunk][ci][tap][COUTC] so per-channel weights are one contiguous s_load
// block. DCN: 4 waves/block, one deformable group per wave, NHWC input.
// ---------------------------------------------------------------------------

#define BDIM 256

template<int CC>
__device__ __forceinline__ void fma9(const float (&v)[9], const float* __restrict__ wp,
                                     float (&acc)[CC])
{
#pragma unroll
    for (int t = 0; t < 9; ++t)
#pragma unroll
        for (int o = 0; o < CC; ++o)
            acc[o] = fmaf(v[t], wp[t * CC + o], acc[o]);
}

template<int C0, int C1, int COUTC, int STRIDE, bool LRELU>
__global__ __launch_bounds__(BDIM, 4)
void conv3x3_k(const float* __restrict__ in0, const float* __restrict__ in1,
               const float* __restrict__ wt,   // [nChunk][CIN][9][COUTC]
               const float* __restrict__ bias,
               float* __restrict__ out,
               int Hin, int Win, int Hout, int Wout,
               int coutTotal, int nChunk)
{
    constexpr int CIN = C0 + C1;
    const int bz = blockIdx.z;
    const int b = bz / nChunk;
    const int chunk = bz - b * nChunk;
    const int cout_base = chunk * COUTC;

    const int ox = blockIdx.x * 16 + (threadIdx.x & 15);
    const int oy = blockIdx.y * 16 + (threadIdx.x >> 4);
    if (ox >= Wout || oy >= Hout) return;

    const int iy0 = oy * STRIDE - 1;
    const int ix0 = ox * STRIDE - 1;

    int off[9]; float msk[9];
#pragma unroll
    for (int t = 0; t < 9; ++t) {
        const int yy = iy0 + t / 3, xx = ix0 + t % 3;
        const bool ok = ((unsigned)yy < (unsigned)Hin) & ((unsigned)xx < (unsigned)Win);
        const int yc = min(max(yy, 0), Hin - 1);
        const int xc = min(max(xx, 0), Win - 1);
        off[t] = yc * Win + xc;
        msk[t] = ok ? 1.f : 0.f;
    }

    float acc[COUTC];
#pragma unroll
    for (int o = 0; o < COUTC; ++o) acc[o] = bias[cout_base + o];

    const int plane = Hin * Win;
    const float* b0 = in0 + (size_t)b * C0 * plane;
    const float* b1 = (C1 > 0) ? in1 + (size_t)b * C1 * plane : nullptr;
    const float* wchunk = wt + (size_t)chunk * CIN * 9 * COUTC;

    float cur[9], nxt[9];
#pragma unroll
    for (int t = 0; t < 9; ++t) cur[t] = b0[off[t]] * msk[t];

    for (int c = 0; c < C0 - 1; ++c) {
        const float* nb = b0 + (size_t)(c + 1) * plane;
#pragma unroll
        for (int t = 0; t < 9; ++t) nxt[t] = nb[off[t]] * msk[t];
        fma9<COUTC>(cur, wchunk + (size_t)c * 9 * COUTC, acc);
#pragma unroll
        for (int t = 0; t < 9; ++t) cur[t] = nxt[t];
    }
    if (C1 > 0) {
#pragma unroll
        for (int t = 0; t < 9; ++t) nxt[t] = b1[off[t]] * msk[t];
        fma9<COUTC>(cur, wchunk + (size_t)(C0 - 1) * 9 * COUTC, acc);
#pragma unroll
        for (int t = 0; t < 9; ++t) cur[t] = nxt[t];
        for (int c = 0; c < C1 - 1; ++c) {
            const float* nb = b1 + (size_t)(c + 1) * plane;
#pragma unroll
            for (int t = 0; t < 9; ++t) nxt[t] = nb[off[t]] * msk[t];
            fma9<COUTC>(cur, wchunk + (size_t)(C0 + c) * 9 * COUTC, acc);
#pragma unroll
            for (int t = 0; t < 9; ++t) cur[t] = nxt[t];
        }
        fma9<COUTC>(cur, wchunk + (size_t)(CIN - 1) * 9 * COUTC, acc);
    } else {
        fma9<COUTC>(cur, wchunk + (size_t)(C0 - 1) * 9 * COUTC, acc);
    }

    float* op = out + ((size_t)b * coutTotal + cout_base) * ((size_t)Hout * Wout)
                    + (size_t)oy * Wout + ox;
#pragma unroll
    for (int o = 0; o < COUTC; ++o) {
        float r = acc[o];
        if (LRELU) r = (r >= 0.f) ? r : 0.1f * r;
        op[(size_t)o * Hout * Wout] = r;
    }
}

// Transpose all conv weights [O][I][3][3] -> [chunk][i][t][CC] in one launch.
struct WTArgs {
    const float* src[11];
    float* dst[11];
    int O[11], I[11], CC[11];
};

__global__ __launch_bounds__(BDIM)
void wtall_k(WTArgs a)
{
    const int z = blockIdx.z;
    const int O = a.O[z], I = a.I[z], CC = a.CC[z];
    const int n = O * I * 9;
    const int idx = blockIdx.x * BDIM + threadIdx.x;
    if (idx >= n) return;
    const int oc = idx % CC;
    int r = idx / CC;
    const int t = r % 9; r /= 9;
    const int i = r % I;
    const int chunk = r / I;
    const int o = chunk * CC + oc;
    a.dst[z][idx] = a.src[z][(o * I + i) * 9 + t];
}

// Bilinear 2x upsample, half-pixel centers, edge clamp.
__global__ __launch_bounds__(BDIM)
void up2_k(const float* __restrict__ in, float* __restrict__ out,
           int C, int Hin, int Win)
{
    const int Hout = Hin * 2, Wout = Win * 2;
    const int idx = blockIdx.x * BDIM + threadIdx.x;
    const int total = C * Hout * Wout;
    if (idx >= total) return;
    const int x = idx % Wout;
    int t = idx / Wout;
    const int y = t % Hout;
    const int c = t / Hout;

    const float sy = (y + 0.5f) * 0.5f - 0.5f;
    const float sx = (x + 0.5f) * 0.5f - 0.5f;
    const float y0f = floorf(sy), x0f = floorf(sx);
    const float wy = sy - y0f, wx = sx - x0f;
    const int y0 = (int)y0f, x0 = (int)x0f;
    const int y0c = min(max(y0, 0), Hin - 1);
    const int y1c = min(max(y0 + 1, 0), Hin - 1);
    const int x0c = min(max(x0, 0), Win - 1);
    const int x1c = min(max(x0 + 1, 0), Win - 1);
    const float* img = in + (size_t)c * Hin * Win;
    const float v00 = img[y0c * Win + x0c];
    const float v01 = img[y0c * Win + x1c];
    const float v10 = img[y1c * Win + x0c];
    const float v11 = img[y1c * Win + x1c];
    out[idx] = (1.f - wy) * ((1.f - wx) * v00 + wx * v01)
             + wy * ((1.f - wx) * v10 + wx * v11);
}

// NCHW [4][32][192][192] -> NHWC [4][192][192][32]
__global__ __launch_bounds__(BDIM)
void nhwc_k(const float* __restrict__ in, float* __restrict__ out, int H, int W)
{
    const int idx = blockIdx.x * BDIM + threadIdx.x;
    if (idx >= 4 * 32 * H * W) return;
    const int c = idx & 31;
    int t = idx >> 5;
    const int x = t % W; t /= W;
    const int y = t % H;
    const int b = t / H;
    out[idx] = in[(((size_t)b * 32 + c) * H + y) * W + x];
}

// w_dcn [32o][32i][9k] -> wt [9k][32i][32o]
__global__ __launch_bounds__(BDIM)
void wtr_k(const float* __restrict__ in, float* __restrict__ out)
{
    const int idx = blockIdx.x * BDIM + threadIdx.x;
    if (idx >= 9 * 32 * 32) return;
    const int o = idx & 31;
    const int i = (idx >> 5) & 31;
    const int k = idx >> 10;
    out[idx] = in[((size_t)o * 32 + i) * 9 + k];
}

// Modulated deformable conv (DCNv2), 3x3, pad 1, stride 1, DG=4 groups.
__global__ __launch_bounds__(BDIM)
void dcn_k(const float* __restrict__ xt,   // NHWC [B][H][W][32]
           const float* __restrict__ om,   // planar [B][108][H][W]
           const float* __restrict__ wt,   // [9][32][32] (k, cin, cout)
           const float* __restrict__ bias,
           float* __restrict__ out, int H, int W)
{
    const int lane = threadIdx.x & 63;
    const int gu = __builtin_amdgcn_readfirstlane(threadIdx.x >> 6);
    const int P = blockIdx.x * 64;
    const int b = P / (H * W);
    int p = P - b * H * W;
    const int y = p / W;
    const int x = (p - y * W) + lane;
    const size_t plane = (size_t)H * W;

    __shared__ float red[4][64][33];

    float acc[32];
#pragma unroll
    for (int o = 0; o < 32; ++o) acc[o] = 0.f;

    const float* omb = om + ((size_t)b * 108 + gu * 9) * plane + (size_t)y * W + x;
    const float* xb  = xt + (size_t)b * plane * 32 + gu * 8;

#pragma unroll
    for (int k = 0; k < 9; ++k) {
        const float offy = omb[(size_t)k * plane];
        const float offx = omb[(size_t)(36 + k) * plane];
        const float ml   = omb[(size_t)(72 + k) * plane];
        const float m = 1.f / (1.f + __expf(-ml));

        const float py = offy + (float)y + (float)(k / 3 - 1);
        const float px = offx + (float)x + (float)(k % 3 - 1);
        const float y0f = floorf(py), x0f = floorf(px);
        const int y0 = (int)y0f, x0 = (int)x0f;
        const float wy1 = py - y0f, wx1 = px - x0f;
        const float wy0 = 1.f - wy1, wx0 = 1.f - wx1;

        const bool y0ok = (unsigned)y0 < (unsigned)H;
        const bool y1ok = (unsigned)(y0 + 1) < (unsigned)H;
        const bool x0ok = (unsigned)x0 < (unsigned)W;
        const bool x1ok = (unsigned)(x0 + 1) < (unsigned)W;
        const int y0c = min(max(y0, 0), H - 1);
        const int y1c = min(max(y0 + 1, 0), H - 1);
        const int x0c = min(max(x0, 0), W - 1);
        const int x1c = min(max(x0 + 1, 0), W - 1);

        const float w00 = wy0 * wx0 * ((y0ok && x0ok) ? 1.f : 0.f) * m;
        const float w01 = wy0 * wx1 * ((y0ok && x1ok) ? 1.f : 0.f) * m;
        const float w10 = wy1 * wx0 * ((y1ok && x0ok) ? 1.f : 0.f) * m;
        const float w11 = wy1 * wx1 * ((y1ok && x1ok) ? 1.f : 0.f) * m;

        const float* c00 = xb + ((size_t)y0c * W + x0c) * 32;
        const float* c01 = xb + ((size_t)y0c * W + x1c) * 32;
        const float* c10 = xb + ((size_t)y1c * W + x0c) * 32;
        const float* c11 = xb + ((size_t)y1c * W + x1c) * 32;

        float4 a00 = *(const float4*)(c00), b00 = *(const float4*)(c00 + 4);
        float4 a01 = *(const float4*)(c01), b01 = *(const float4*)(c01 + 4);
        float4 a10 = *(const float4*)(c10), b10 = *(const float4*)(c10 + 4);
        float4 a11 = *(const float4*)(c11), b11 = *(const float4*)(c11 + 4);

        float s[8];
        s[0] = w00 * a00.x + w01 * a01.x + w10 * a10.x + w11 * a11.x;
        s[1] = w00 * a00.y + w01 * a01.y + w10 * a10.y + w11 * a11.y;
        s[2] = w00 * a00.z + w01 * a01.z + w10 * a10.z + w11 * a11.z;
        s[3] = w00 * a00.w + w01 * a01.w + w10 * a10.w + w11 * a11.w;
        s[4] = w00 * b00.x + w01 * b01.x + w10 * b10.x + w11 * b11.x;
        s[5] = w00 * b00.y + w01 * b01.y + w10 * b10.y + w11 * b11.y;
        s[6] = w00 * b00.z + w01 * b01.z + w10 * b10.z + w11 * b11.z;
        s[7] = w00 * b00.w + w01 * b01.w + w10 * b10.w + w11 * b11.w;

        const float* wk = wt + ((size_t)k * 32 + gu * 8) * 32;
#pragma unroll
        for (int c = 0; c < 8; ++c) {
#pragma unroll
            for (int o = 0; o < 32; ++o)
                acc[o] = fmaf(s[c], wk[c * 32 + o], acc[o]);
        }
    }

#pragma unroll
    for (int o = 0; o < 32; ++o) red[gu][lane][o] = acc[o];
    __syncthreads();

    float* op = out + (size_t)b * 32 * plane + (size_t)y * W + x;
#pragma unroll
    for (int j = 0; j < 8; ++j) {
        const int o = gu * 8 + j;
        float r = bias[o] + red[0][lane][o] + red[1][lane][o]
                          + red[2][lane][o] + red[3][lane][o];
        op[(size_t)o * plane] = r;
    }
}

// ---------------------------------------------------------------------------

extern "C" void kernel_launch(void* const* d_in, const int* in_sizes, int n_in,
                              void* d_out, int out_size, void* d_ws, size_t ws_size,
                              hipStream_t stream)
{
    const float* fea1  = (const float*)d_in[0];
    const float* fea2  = (const float*)d_in[1];
    const float* w1_1  = (const float*)d_in[2];  const float* b1_1 = (const float*)d_in[3];
    const float* w2_1  = (const float*)d_in[4];  const float* b2_1 = (const float*)d_in[5];
    const float* w3_1  = (const float*)d_in[6];  const float* b3_1 = (const float*)d_in[7];
    const float* w4_1  = (const float*)d_in[8];  const float* b4_1 = (const float*)d_in[9];
    const float* w6_1  = (const float*)d_in[10]; const float* b6_1 = (const float*)d_in[11];
    const float* w7_1  = (const float*)d_in[12]; const float* b7_1 = (const float*)d_in[13];
    const float* w1_2  = (const float*)d_in[14]; const float* b1_2 = (const float*)d_in[15];
    const float* w2_2  = (const float*)d_in[16]; const float* b2_2 = (const float*)d_in[17];
    const float* w3_2  = (const float*)d_in[18]; const float* b3_2 = (const float*)d_in[19];
    const float* w4_2  = (const float*)d_in[20]; const float* b4_2 = (const float*)d_in[21];
    const float* w_om  = (const float*)d_in[22]; const float* b_om = (const float*)d_in[23];
    const float* w_dcn = (const float*)d_in[24]; const float* b_dcn= (const float*)d_in[25];

    const int B = 4, H = 192, W = 192;
    const size_t sz192 = (size_t)B * 32 * H * W * 4;
    const size_t sz96  = (size_t)B * 32 * (H/2) * (W/2) * 4;
    const size_t sz48  = (size_t)B * 32 * (H/4) * (W/4) * 4;
    const size_t szOM  = (size_t)B * 108 * H * W * 4;

    char* ws = (char*)d_ws;
    float* bufA = (float*)(ws + 0);
    float* bufB = (float*)(ws + sz192);
    float* bufC = (float*)(ws + 2 * sz192);
    float* bufD = (float*)(ws + 2 * sz192 + sz96);
    float* bufE = (float*)(ws + 2 * sz192 + 2 * sz96);
    float* bufF = (float*)(ws + 2 * sz192 + 2 * sz96 + sz48);
    float* bufG = (float*)(ws + 2 * sz192 + 2 * sz96 + 2 * sz48);
    float* bufH = (float*)(ws + 0);
    float* bufI = (float*)(ws + 2 * sz192);
    float* bufJ = (float*)(ws + 0);
    float* bufK = (float*)(ws + 2 * sz192 + 3 * sz96 + 2 * sz48);
    float* bufL = (float*)(ws + 0);
    float* bufM = (float*)(ws + sz192);                       // om planar
    float* fea2t= (float*)(ws + 0);
    float* wtb  = (float*)(ws + sz192 + szOM);                // dcn wt, 36864 B
    float* wtc  = (float*)(ws + sz192 + szOM + 36864);        // conv wts, 603648 B

    // transposed conv-weight offsets (floats)
    const int WOFF[11] = {0, 18432, 27648, 36864, 46080, 55296,
                          64512, 82944, 92160, 110592, 119808};

    dim3 blk(BDIM, 1, 1);

    // 0. weight transposes
    {
        WTArgs a;
        const float* srcs[11] = {w1_1, w2_1, w3_1, w4_1, w6_1, w7_1,
                                 w1_2, w2_2, w3_2, w4_2, w_om};
        const int Os[11] = {32,32,32,32,32,32,32,32,32,32,108};
        const int Is[11] = {64,32,32,32,32,32,64,32,64,32,32};
        const int Cs[11] = {8, 8, 8, 8, 4, 4, 8, 8, 8, 8, 12};
        for (int i = 0; i < 11; ++i) {
            a.src[i] = srcs[i]; a.dst[i] = wtc + WOFF[i];
            a.O[i] = Os[i]; a.I[i] = Is[i]; a.CC[i] = Cs[i];
        }
        wtall_k<<<dim3(122, 1, 11), blk, 0, stream>>>(a);
        wtr_k<<<dim3(36), blk, 0, stream>>>(w_dcn, wtb);
    }

    dim3 g192(12, 12, 16);
    dim3 g96(6, 6, 16);
    dim3 g48(3, 3, 32);
    dim3 gom(12, 12, 36);

    // 1. off = lrelu(conv1_1(cat(fea1, fea2)))
    conv3x3_k<32, 32, 8, 1, true><<<g192, blk, 0, stream>>>(
        fea1, fea2, wtc + WOFF[0], b1_1, bufA, H, W, H, W, 32, 4);
    // 2. off1 = lrelu(conv2_1(off))
    conv3x3_k<32, 0, 8, 1, true><<<g192, blk, 0, stream>>>(
        bufA, nullptr, wtc + WOFF[1], b2_1, bufB, H, W, H, W, 32, 4);
    // 3. off2a = lrelu(conv3_1(off1, s2))
    conv3x3_k<32, 0, 8, 2, true><<<g96, blk, 0, stream>>>(
        bufB, nullptr, wtc + WOFF[2], b3_1, bufC, H, W, H/2, W/2, 32, 4);
    // 4. off2 = lrelu(conv4_1(off2a))
    conv3x3_k<32, 0, 8, 1, true><<<g96, blk, 0, stream>>>(
        bufC, nullptr, wtc + WOFF[3], b4_1, bufD, H/2, W/2, H/2, W/2, 32, 4);
    // 5. off3a = lrelu(conv6_1(off2, s2))
    conv3x3_k<32, 0, 4, 2, true><<<g48, blk, 0, stream>>>(
        bufD, nullptr, wtc + WOFF[4], b6_1, bufE, H/2, W/2, H/4, W/4, 32, 8);
    // 6. off3 = lrelu(conv7_1(off3a))
    conv3x3_k<32, 0, 4, 1, true><<<g48, blk, 0, stream>>>(
        bufE, nullptr, wtc + WOFF[5], b7_1, bufF, H/4, W/4, H/4, W/4, 32, 8);
    // 7. up96 = up2(off3)
    {
        int total = B * 32 * (H/2) * (W/2);
        up2_k<<<dim3((total + BDIM - 1) / BDIM), blk, 0, stream>>>(
            bufF, bufG, B * 32, H/4, W/4);
    }
    // 8. t = lrelu(conv1_2(cat(up96, off2)))
    conv3x3_k<32, 32, 8, 1, true><<<g96, blk, 0, stream>>>(
        bufG, bufD, wtc + WOFF[6], b1_2, bufH, H/2, W/2, H/2, W/2, 32, 4);
    // 9. t2 = lrelu(conv2_2(t))
    conv3x3_k<32, 0, 8, 1, true><<<g96, blk, 0, stream>>>(
        bufH, nullptr, wtc + WOFF[7], b2_2, bufI, H/2, W/2, H/2, W/2, 32, 4);
    // 10. up192 = up2(t2)
    {
        int total = B * 32 * H * W;
        up2_k<<<dim3((total + BDIM - 1) / BDIM), blk, 0, stream>>>(
            bufI, bufJ, B * 32, H/2, W/2);
    }
    // 11. off = lrelu(conv3_2(cat(up192, off1)))
    conv3x3_k<32, 32, 8, 1, true><<<g192, blk, 0, stream>>>(
        bufJ, bufB, wtc + WOFF[8], b3_2, bufK, H, W, H, W, 32, 4);
    // 12. base_offset = conv4_2(off)   (no lrelu)
    conv3x3_k<32, 0, 8, 1, false><<<g192, blk, 0, stream>>>(
        bufK, nullptr, wtc + WOFF[9], b4_2, bufL, H, W, H, W, 32, 4);
    // 13. om = conv_om(base_offset)  32 -> 108  (no lrelu)
    conv3x3_k<32, 0, 12, 1, false><<<gom, blk, 0, stream>>>(
        bufL, nullptr, wtc + WOFF[10], b_om, bufM, H, W, H, W, 108, 9);
    // 13b. fea2 -> NHWC (bufL slot dead now)
    {
        int total = B * 32 * H * W;
        nhwc_k<<<dim3((total + BDIM - 1) / BDIM), blk, 0, stream>>>(fea2, fea2t, H, W);
    }
    // 14. out = deform_conv(fea2, om)
    {
        int nblocks = B * H * W / 64;
        dcn_k<<<dim3(nblocks), blk, 0, stream>>>(
            fea2t, bufM, wtb, b_dcn, (float*)d_out, H, W);
    }
}

// Round 4
// 406.216 us; speedup vs baseline: 6.3323x; 1.8923x over previous
//
#include <hip/hip_runtime.h>
#include <math.h>

// ---------------------------------------------------------------------------
// DCN_Align on MI355X. Convs = implicit-GEMM on MFMA bf16 (16x16x32):
// per tap, D[cout][pix] += W_t[cout][cin] * X_t[cin][pix]. NHWC bf16
// intermediates; A(weights) pre-packed to fragment layout; fp32 accum;
// bias+lrelu+bf16-RNE epilogue. DCN stays fp32 (om read as bf16).
// ---------------------------------------------------------------------------

#define BDIM 256

typedef __attribute__((ext_vector_type(8))) short short8v;
typedef __attribute__((ext_vector_type(4))) float f32x4;

__device__ __forceinline__ unsigned short f2bf(float f) {
    unsigned u = __builtin_bit_cast(unsigned, f);
    u = (u + 0x7FFF + ((u >> 16) & 1)) >> 16;   // round-to-nearest-even
    return (unsigned short)u;
}
__device__ __forceinline__ float bf2f(unsigned short h) {
    unsigned u = ((unsigned)h) << 16;
    return __builtin_bit_cast(float, u);
}

// ---------------------------------------------------------------------------
// MFMA conv: wave handles NT tiles of 16 consecutive x-pixels in one row.
// B-frag: lane l -> pixel (l&15), channels (l>>4)*8+j (16B NHWC load).
// A-frag: lane l -> cout h*16+(l&15), channels (l>>4)*8+j (pre-packed).
// C/D: col(pixel)=lane&15, row(cout)=(lane>>4)*4+reg  [m89-verified].
template<int NPASS, int NHALF, int NT, int STRIDE, bool LRELU>
__global__ __launch_bounds__(BDIM, 2)
void convm_k(const short* __restrict__ in0, const short* __restrict__ in1,
             const short* __restrict__ wf,   // [pass][tap][half][lane][8] bf16
             const float* __restrict__ bias,
             short* __restrict__ out,        // NHWC bf16, channel stride OCS
             int Hin, int Win, int Hout, int Wout, int OCS, int coutTot)
{
    const int lane = threadIdx.x & 63;
    const int wid  = blockIdx.x * 4 + (threadIdx.x >> 6);
    const int segs = Wout / (16 * NT);
    const int b  = wid / (Hout * segs);
    int r = wid - b * (Hout * segs);
    const int oy = r / segs;
    const int x0 = (r - oy * segs) * (16 * NT);
    const int lp = lane & 15;
    const int g  = lane >> 4;

    f32x4 acc[NT][NHALF];
#pragma unroll
    for (int nt = 0; nt < NT; ++nt)
#pragma unroll
        for (int h = 0; h < NHALF; ++h)
            acc[nt][h] = (f32x4){0.f, 0.f, 0.f, 0.f};

    const size_t inPlane = (size_t)Hin * Win * 32;
    const short8v zero = {};

#pragma unroll
    for (int pass = 0; pass < NPASS; ++pass) {
        const short* inp = (pass == 0 ? in0 : in1) + (size_t)b * inPlane;

        short8v awc[(NHALF <= 2) ? 9 * NHALF : 1];
        if constexpr (NHALF <= 2) {
#pragma unroll
            for (int t = 0; t < 9; ++t)
#pragma unroll
                for (int h = 0; h < NHALF; ++h)
                    awc[t * NHALF + h] = *(const short8v*)(
                        wf + ((((size_t)pass * 9 + t) * NHALF + h) * 64 + lane) * 8);
        }

#pragma unroll
        for (int t = 0; t < 9; ++t) {
            const int iy = oy * STRIDE + t / 3 - 1;
            const bool rowok = (unsigned)iy < (unsigned)Hin;
            const int iyc = min(max(iy, 0), Hin - 1);
#pragma unroll
            for (int nt = 0; nt < NT; ++nt) {
                const int ox = x0 + nt * 16 + lp;
                const int ix = ox * STRIDE + t % 3 - 1;
                const bool ok = rowok & ((unsigned)ix < (unsigned)Win);
                const int ixc = min(max(ix, 0), Win - 1);
                short8v bv = *(const short8v*)(inp + ((size_t)iyc * Win + ixc) * 32 + g * 8);
                bv = ok ? bv : zero;
#pragma unroll
                for (int h = 0; h < NHALF; ++h) {
                    short8v av;
                    if constexpr (NHALF <= 2)
                        av = awc[t * NHALF + h];
                    else
                        av = *(const short8v*)(
                            wf + ((((size_t)pass * 9 + t) * NHALF + h) * 64 + lane) * 8);
                    acc[nt][h] = __builtin_amdgcn_mfma_f32_16x16x32_bf16(
                        av, bv, acc[nt][h], 0, 0, 0);
                }
            }
        }
    }

    const size_t outBase = ((size_t)b * Hout + oy) * Wout;
#pragma unroll
    for (int nt = 0; nt < NT; ++nt) {
        const int p = x0 + nt * 16 + lp;
        short* op = out + (outBase + p) * OCS;
#pragma unroll
        for (int h = 0; h < NHALF; ++h) {
            ushort4 st;
#pragma unroll
            for (int j = 0; j < 4; ++j) {
                const int co = h * 16 + g * 4 + j;
                float v = acc[nt][h][j] + bias[min(co, coutTot - 1)];
                if (LRELU) v = (v >= 0.f) ? v : 0.1f * v;
                ((unsigned short*)&st)[j] = f2bf(v);
            }
            const int co0 = h * 16 + g * 4;
            if (co0 < coutTot)
                *(ushort4*)(op + co0) = st;
        }
    }
}

// ---------------------------------------------------------------------------
// Weight prep: [O][I][3][3] fp32 -> fragment layout bf16.
struct WPArgs {
    const float* src[11];
    int off[11];      // dst offset in shorts
    int npass[11], nhalf[11], O[11];
};

__global__ __launch_bounds__(BDIM)
void wprep_k(WPArgs a, short* __restrict__ wbase)
{
    const int z = blockIdx.z;
    const int n = a.npass[z] * 9 * a.nhalf[z] * 512;
    const int idx = blockIdx.x * BDIM + threadIdx.x;
    if (idx >= n) return;
    const int j = idx & 7;
    const int l = (idx >> 3) & 63;
    int r = idx >> 9;
    const int h = r % a.nhalf[z]; r /= a.nhalf[z];
    const int t = r % 9;
    const int pass = r / 9;
    const int I = a.npass[z] * 32;
    const int cout = h * 16 + (l & 15);
    const int cin  = pass * 32 + (l >> 4) * 8 + j;
    float v = (cout < a.O[z]) ? a.src[z][((size_t)cout * I + cin) * 9 + t] : 0.f;
    wbase[a.off[z] + idx] = (short)f2bf(v);
}

// fea NCHW fp32 -> NHWC bf16 (two tensors in one launch via z)
__global__ __launch_bounds__(BDIM)
void cvtnhwc_k(const float* __restrict__ s0, const float* __restrict__ s1,
               short* __restrict__ d0, short* __restrict__ d1, int H, int W)
{
    const float* s = blockIdx.z ? s1 : s0;
    short* d = blockIdx.z ? d1 : d0;
    const int idx = blockIdx.x * BDIM + threadIdx.x;
    if (idx >= 4 * 32 * H * W) return;
    const int c = idx & 31;
    int t = idx >> 5;
    const int x = t % W; t /= W;
    const int y = t % H;
    const int b = t / H;
    d[idx] = (short)f2bf(s[(((size_t)b * 32 + c) * H + y) * W + x]);
}

// Bilinear 2x upsample, NHWC bf16, half-pixel centers, edge clamp.
__global__ __launch_bounds__(BDIM)
void up2b_k(const short* __restrict__ in, short* __restrict__ out,
            int Hin, int Win)
{
    const int Hout = 2 * Hin, Wout = 2 * Win;
    const int idx = blockIdx.x * BDIM + threadIdx.x;
    if (idx >= 4 * Hout * Wout * 4) return;
    const int cg = idx & 3;
    int t = idx >> 2;
    const int x = t % Wout; t /= Wout;
    const int y = t % Hout;
    const int b = t / Hout;

    const float sy = (y + 0.5f) * 0.5f - 0.5f;
    const float sx = (x + 0.5f) * 0.5f - 0.5f;
    const float y0f = floorf(sy), x0f = floorf(sx);
    const float wy = sy - y0f, wx = sx - x0f;
    const int y0 = (int)y0f, x0 = (int)x0f;
    const int y0c = min(max(y0, 0), Hin - 1);
    const int y1c = min(max(y0 + 1, 0), Hin - 1);
    const int x0c = min(max(x0, 0), Win - 1);
    const int x1c = min(max(x0 + 1, 0), Win - 1);

    const short* base = in + (size_t)b * Hin * Win * 32 + cg * 8;
    short8v v00 = *(const short8v*)(base + ((size_t)y0c * Win + x0c) * 32);
    short8v v01 = *(const short8v*)(base + ((size_t)y0c * Win + x1c) * 32);
    short8v v10 = *(const short8v*)(base + ((size_t)y1c * Win + x0c) * 32);
    short8v v11 = *(const short8v*)(base + ((size_t)y1c * Win + x1c) * 32);

    short8v o;
#pragma unroll
    for (int j = 0; j < 8; ++j) {
        float f = (1.f - wy) * ((1.f - wx) * bf2f((unsigned short)v00[j]) +
                                wx * bf2f((unsigned short)v01[j]))
                + wy * ((1.f - wx) * bf2f((unsigned short)v10[j]) +
                        wx * bf2f((unsigned short)v11[j]));
        o[j] = (short)f2bf(f);
    }
    short* op = out + (size_t)b * Hout * Wout * 32 + ((size_t)y * Wout + x) * 32 + cg * 8;
    *(short8v*)op = o;
}

// NCHW fp32 -> NHWC fp32 (for dcn input)
__global__ __launch_bounds__(BDIM)
void nhwc_k(const float* __restrict__ in, float* __restrict__ out, int H, int W)
{
    const int idx = blockIdx.x * BDIM + threadIdx.x;
    if (idx >= 4 * 32 * H * W) return;
    const int c = idx & 31;
    int t = idx >> 5;
    const int x = t % W; t /= W;
    const int y = t % H;
    const int b = t / H;
    out[idx] = in[(((size_t)b * 32 + c) * H + y) * W + x];
}

// w_dcn [32o][32i][9k] -> wt [9k][32i][32o]
__global__ __launch_bounds__(BDIM)
void wtr_k(const float* __restrict__ in, float* __restrict__ out)
{
    const int idx = blockIdx.x * BDIM + threadIdx.x;
    if (idx >= 9 * 32 * 32) return;
    const int o = idx & 31;
    const int i = (idx >> 5) & 31;
    const int k = idx >> 10;
    out[idx] = in[((size_t)o * 32 + i) * 9 + k];
}

// Modulated deformable conv (DCNv2). om is NHWC bf16 with channel stride 112.
__global__ __launch_bounds__(BDIM)
void dcn_k(const float* __restrict__ xt,   // NHWC fp32 [B][H][W][32]
           const short* __restrict__ om,   // NHWC bf16 [B][H][W][112]
           const float* __restrict__ wt,   // [9][32][32] (k, cin, cout)
           const float* __restrict__ bias,
           float* __restrict__ out, int H, int W)
{
    const int lane = threadIdx.x & 63;
    const int gu = __builtin_amdgcn_readfirstlane(threadIdx.x >> 6);
    const int P = blockIdx.x * 64;
    const int b = P / (H * W);
    int p = P - b * H * W;
    const int y = p / W;
    const int x = (p - y * W) + lane;
    const size_t plane = (size_t)H * W;

    __shared__ float red[4][64][33];

    float acc[32];
#pragma unroll
    for (int o = 0; o < 32; ++o) acc[o] = 0.f;

    const short* omb = om + ((size_t)b * plane + (size_t)y * W + x) * 112;
    const float* xb  = xt + (size_t)b * plane * 32 + gu * 8;

#pragma unroll
    for (int k = 0; k < 9; ++k) {
        const float offy = bf2f((unsigned short)omb[gu * 9 + k]);
        const float offx = bf2f((unsigned short)omb[36 + gu * 9 + k]);
        const float ml   = bf2f((unsigned short)omb[72 + gu * 9 + k]);
        const float m = 1.f / (1.f + __expf(-ml));

        const float py = offy + (float)y + (float)(k / 3 - 1);
        const float px = offx + (float)x + (float)(k % 3 - 1);
        const float y0f = floorf(py), x0f = floorf(px);
        const int y0 = (int)y0f, x0 = (int)x0f;
        const float wy1 = py - y0f, wx1 = px - x0f;
        const float wy0 = 1.f - wy1, wx0 = 1.f - wx1;

        const bool y0ok = (unsigned)y0 < (unsigned)H;
        const bool y1ok = (unsigned)(y0 + 1) < (unsigned)H;
        const bool x0ok = (unsigned)x0 < (unsigned)W;
        const bool x1ok = (unsigned)(x0 + 1) < (unsigned)W;
        const int y0c = min(max(y0, 0), H - 1);
        const int y1c = min(max(y0 + 1, 0), H - 1);
        const int x0c = min(max(x0, 0), W - 1);
        const int x1c = min(max(x0 + 1, 0), W - 1);

        const float w00 = wy0 * wx0 * ((y0ok && x0ok) ? 1.f : 0.f) * m;
        const float w01 = wy0 * wx1 * ((y0ok && x1ok) ? 1.f : 0.f) * m;
        const float w10 = wy1 * wx0 * ((y1ok && x0ok) ? 1.f : 0.f) * m;
        const float w11 = wy1 * wx1 * ((y1ok && x1ok) ? 1.f : 0.f) * m;

        const float* c00 = xb + ((size_t)y0c * W + x0c) * 32;
        const float* c01 = xb + ((size_t)y0c * W + x1c) * 32;
        const float* c10 = xb + ((size_t)y1c * W + x0c) * 32;
        const float* c11 = xb + ((size_t)y1c * W + x1c) * 32;

        float4 a00 = *(const float4*)(c00), b00 = *(const float4*)(c00 + 4);
        float4 a01 = *(const float4*)(c01), b01 = *(const float4*)(c01 + 4);
        float4 a10 = *(const float4*)(c10), b10 = *(const float4*)(c10 + 4);
        float4 a11 = *(const float4*)(c11), b11 = *(const float4*)(c11 + 4);

        float s[8];
        s[0] = w00 * a00.x + w01 * a01.x + w10 * a10.x + w11 * a11.x;
        s[1] = w00 * a00.y + w01 * a01.y + w10 * a10.y + w11 * a11.y;
        s[2] = w00 * a00.z + w01 * a01.z + w10 * a10.z + w11 * a11.z;
        s[3] = w00 * a00.w + w01 * a01.w + w10 * a10.w + w11 * a11.w;
        s[4] = w00 * b00.x + w01 * b01.x + w10 * b10.x + w11 * b11.x;
        s[5] = w00 * b00.y + w01 * b01.y + w10 * b10.y + w11 * b11.y;
        s[6] = w00 * b00.z + w01 * b01.z + w10 * b10.z + w11 * b11.z;
        s[7] = w00 * b00.w + w01 * b01.w + w10 * b10.w + w11 * b11.w;

        const float* wk = wt + ((size_t)k * 32 + gu * 8) * 32;
#pragma unroll
        for (int c = 0; c < 8; ++c) {
#pragma unroll
            for (int o = 0; o < 32; ++o)
                acc[o] = fmaf(s[c], wk[c * 32 + o], acc[o]);
        }
    }

#pragma unroll
    for (int o = 0; o < 32; ++o) red[gu][lane][o] = acc[o];
    __syncthreads();

    float* op = out + (size_t)b * 32 * plane + (size_t)y * W + x;
#pragma unroll
    for (int j = 0; j < 8; ++j) {
        const int o = gu * 8 + j;
        float r = bias[o] + red[0][lane][o] + red[1][lane][o]
                          + red[2][lane][o] + red[3][lane][o];
        op[(size_t)o * plane] = r;
    }
}

// ---------------------------------------------------------------------------

extern "C" void kernel_launch(void* const* d_in, const int* in_sizes, int n_in,
                              void* d_out, int out_size, void* d_ws, size_t ws_size,
                              hipStream_t stream)
{
    const float* fea1  = (const float*)d_in[0];
    const float* fea2  = (const float*)d_in[1];
    const float* w1_1  = (const float*)d_in[2];  const float* b1_1 = (const float*)d_in[3];
    const float* w2_1  = (const float*)d_in[4];  const float* b2_1 = (const float*)d_in[5];
    const float* w3_1  = (const float*)d_in[6];  const float* b3_1 = (const float*)d_in[7];
    const float* w4_1  = (const float*)d_in[8];  const float* b4_1 = (const float*)d_in[9];
    const float* w6_1  = (const float*)d_in[10]; const float* b6_1 = (const float*)d_in[11];
    const float* w7_1  = (const float*)d_in[12]; const float* b7_1 = (const float*)d_in[13];
    const float* w1_2  = (const float*)d_in[14]; const float* b1_2 = (const float*)d_in[15];
    const float* w2_2  = (const float*)d_in[16]; const float* b2_2 = (const float*)d_in[17];
    const float* w3_2  = (const float*)d_in[18]; const float* b3_2 = (const float*)d_in[19];
    const float* w4_2  = (const float*)d_in[20]; const float* b4_2 = (const float*)d_in[21];
    const float* w_om  = (const float*)d_in[22]; const float* b_om = (const float*)d_in[23];
    const float* w_dcn = (const float*)d_in[24]; const float* b_dcn= (const float*)d_in[25];

    const int H = 192, W = 192;
    char* ws = (char*)d_ws;

    // byte offsets (bump-allocated with reuse; peak ~71.2 MB)
    short* fea1b = (short*)(ws + 0);          // bf16 NHWC 192  (9.44 MB)
    short* fea2b = (short*)(ws + 9437184);
    short* bufA  = (short*)(ws + 18874368);   // off      192
    short* bufB  = (short*)(ws + 28311552);   // off1     192 (lives to conv3_2)
    short* bufC  = (short*)(ws + 0);          // off2a    96  (fea1b dead)
    short* bufD  = (short*)(ws + 2359296);    // off2     96  (lives to conv1_2)
    short* bufE  = (short*)(ws + 4718592);    // off3a    48
    short* bufF  = (short*)(ws + 5308416);    // off3     48
    short* bufG  = (short*)(ws + 5898240);    // up96
    short* bufH  = (short*)(ws + 0);          // conv1_2 out 96 (bufC dead)
    short* bufI  = (short*)(ws + 4718592);    // conv2_2 out 96 (E/F dead; G dead after 8)
    short* bufJ  = (short*)(ws + 9437184);    // up192 (fea2b dead)
    short* bufK  = (short*)(ws + 18874368);   // conv3_2 out (bufA dead)
    short* bufL  = (short*)(ws + 0);          // base_offset 192 (H/D/I dead)
    short* om    = (short*)(ws + 37748736);   // NHWC bf16 stride 112 (33.0 MB)
    float* fea2t = (float*)(ws + 9437184);    // NHWC fp32 (J,K dead) 18.9 MB
    short* wfrag = (short*)(ws + 70778880);   // conv weight frags (304 KB)
    float* wtb   = (float*)(ws + 71083008);   // dcn weights (36 KB)

    // fragment offsets in shorts per conv
    const int WOFF[11] = {0, 18432, 27648, 36864, 46080, 55296,
                          64512, 82944, 92160, 110592, 119808};

    dim3 blk(BDIM, 1, 1);

    // 0. weight prep + input conversions
    {
        WPArgs a;
        const float* srcs[11] = {w1_1, w2_1, w3_1, w4_1, w6_1, w7_1,
                                 w1_2, w2_2, w3_2, w4_2, w_om};
        const int NP[11] = {2,1,1,1,1,1,2,1,2,1,1};
        const int NH[11] = {2,2,2,2,2,2,2,2,2,2,7};
        const int Os[11] = {32,32,32,32,32,32,32,32,32,32,108};
        for (int i = 0; i < 11; ++i) {
            a.src[i] = srcs[i]; a.off[i] = WOFF[i];
            a.npass[i] = NP[i]; a.nhalf[i] = NH[i]; a.O[i] = Os[i];
        }
        wprep_k<<<dim3(126, 1, 11), blk, 0, stream>>>(a, wfrag);
        cvtnhwc_k<<<dim3(18432, 1, 2), blk, 0, stream>>>(fea1, fea2, fea1b, fea2b, H, W);
        wtr_k<<<dim3(36), blk, 0, stream>>>(w_dcn, wtb);
    }

    // 1. off = lrelu(conv1_1(cat(fea1, fea2)))           192
    convm_k<2,2,4,1,true><<<dim3(576), blk, 0, stream>>>(
        fea1b, fea2b, wfrag + WOFF[0], b1_1, bufA, 192,192,192,192, 32, 32);
    // 2. off1 = lrelu(conv2_1(off))                      192
    convm_k<1,2,4,1,true><<<dim3(576), blk, 0, stream>>>(
        bufA, nullptr, wfrag + WOFF[1], b2_1, bufB, 192,192,192,192, 32, 32);
    // 3. off2a = lrelu(conv3_1(off1, s2))                96
    convm_k<1,2,3,2,true><<<dim3(192), blk, 0, stream>>>(
        bufB, nullptr, wfrag + WOFF[2], b3_1, bufC, 192,192,96,96, 32, 32);
    // 4. off2 = lrelu(conv4_1(off2a))                    96
    convm_k<1,2,3,1,true><<<dim3(192), blk, 0, stream>>>(
        bufC, nullptr, wfrag + WOFF[3], b4_1, bufD, 96,96,96,96, 32, 32);
    // 5. off3a = lrelu(conv6_1(off2, s2))                48
    convm_k<1,2,3,2,true><<<dim3(48), blk, 0, stream>>>(
        bufD, nullptr, wfrag + WOFF[4], b6_1, bufE, 96,96,48,48, 32, 32);
    // 6. off3 = lrelu(conv7_1(off3a))                    48
    convm_k<1,2,3,1,true><<<dim3(48), blk, 0, stream>>>(
        bufE, nullptr, wfrag + WOFF[5], b7_1, bufF, 48,48,48,48, 32, 32);
    // 7. up96 = up2(off3)
    up2b_k<<<dim3(576), blk, 0, stream>>>(bufF, bufG, 48, 48);
    // 8. t = lrelu(conv1_2(cat(up96, off2)))             96
    convm_k<2,2,3,1,true><<<dim3(192), blk, 0, stream>>>(
        bufG, bufD, wfrag + WOFF[6], b1_2, bufH, 96,96,96,96, 32, 32);
    // 9. t2 = lrelu(conv2_2(t))                          96
    convm_k<1,2,3,1,true><<<dim3(192), blk, 0, stream>>>(
        bufH, nullptr, wfrag + WOFF[7], b2_2, bufI, 96,96,96,96, 32, 32);
    // 10. up192 = up2(t2)
    up2b_k<<<dim3(2304), blk, 0, stream>>>(bufI, bufJ, 96, 96);
    // 11. off = lrelu(conv3_2(cat(up192, off1)))         192
    convm_k<2,2,4,1,true><<<dim3(576), blk, 0, stream>>>(
        bufJ, bufB, wfrag + WOFF[8], b3_2, bufK, 192,192,192,192, 32, 32);
    // 12. base_offset = conv4_2(off)    (no lrelu)       192
    convm_k<1,2,4,1,false><<<dim3(576), blk, 0, stream>>>(
        bufK, nullptr, wfrag + WOFF[9], b4_2, bufL, 192,192,192,192, 32, 32);
    // 13. om = conv_om(base_offset)  32 -> 108 (pad 112) 192
    convm_k<1,7,4,1,false><<<dim3(576), blk, 0, stream>>>(
        bufL, nullptr, wfrag + WOFF[10], b_om, om, 192,192,192,192, 112, 108);
    // 13b. fea2 -> NHWC fp32 (bufJ/bufK region dead)
    nhwc_k<<<dim3(18432), blk, 0, stream>>>(fea2, fea2t, H, W);
    // 14. out = deform_conv(fea2, om)
    dcn_k<<<dim3(4 * H * W / 64), blk, 0, stream>>>(
        fea2t, om, wtb, b_dcn, (float*)d_out, H, W);
}

// Round 5
// 334.141 us; speedup vs baseline: 7.6982x; 1.2157x over previous
//
#include <hip/hip_runtime.h>
#include <math.h>

// ---------------------------------------------------------------------------
// DCN_Align on MI355X. Convs AND deformable conv on MFMA bf16 (16x16x32).
// Conv: per tap, D[cout][pix] += W_t[cout][cin] * X_t[cin][pix]; NHWC bf16.
// DCN: lane l samples pixel (l&15), group (l>>4) -> B-fragment directly;
// 2 MFMAs per tap contract all 32 input channels; no LDS reduction.
// ---------------------------------------------------------------------------

#define BDIM 256

typedef __attribute__((ext_vector_type(8))) short short8v;
typedef __attribute__((ext_vector_type(4))) float f32x4;

__device__ __forceinline__ unsigned short f2bf(float f) {
    unsigned u = __builtin_bit_cast(unsigned, f);
    u = (u + 0x7FFF + ((u >> 16) & 1)) >> 16;   // round-to-nearest-even
    return (unsigned short)u;
}
__device__ __forceinline__ float bf2f(unsigned short h) {
    unsigned u = ((unsigned)h) << 16;
    return __builtin_bit_cast(float, u);
}

// ---------------------------------------------------------------------------
// MFMA conv: wave handles NT tiles of 16 consecutive x-pixels in one row.
// B-frag: lane l -> pixel (l&15), channels (l>>4)*8+j (16B NHWC load).
// A-frag: lane l -> cout h*16+(l&15), channels (l>>4)*8+j (pre-packed).
// C/D: col(pixel)=lane&15, row(cout)=(lane>>4)*4+reg  [verified in-round].
template<int NPASS, int NHALF, int NT, int STRIDE, bool LRELU>
__global__ __launch_bounds__(BDIM, 2)
void convm_k(const short* __restrict__ in0, const short* __restrict__ in1,
             const short* __restrict__ wf,   // [pass][tap][half][lane][8] bf16
             const float* __restrict__ bias,
             short* __restrict__ out,        // NHWC bf16, channel stride OCS
             int Hin, int Win, int Hout, int Wout, int OCS, int coutTot)
{
    const int lane = threadIdx.x & 63;
    const int wid  = blockIdx.x * 4 + (threadIdx.x >> 6);
    const int segs = Wout / (16 * NT);
    const int b  = wid / (Hout * segs);
    int r = wid - b * (Hout * segs);
    const int oy = r / segs;
    const int x0 = (r - oy * segs) * (16 * NT);
    const int lp = lane & 15;
    const int g  = lane >> 4;

    f32x4 acc[NT][NHALF];
#pragma unroll
    for (int nt = 0; nt < NT; ++nt)
#pragma unroll
        for (int h = 0; h < NHALF; ++h)
            acc[nt][h] = (f32x4){0.f, 0.f, 0.f, 0.f};

    const size_t inPlane = (size_t)Hin * Win * 32;
    const short8v zero = {};
    constexpr bool CACHE_A = (NHALF <= 2) && (NT > 1);

#pragma unroll
    for (int pass = 0; pass < NPASS; ++pass) {
        const short* inp = (pass == 0 ? in0 : in1) + (size_t)b * inPlane;

        short8v awc[CACHE_A ? 9 * NHALF : 1];
        if constexpr (CACHE_A) {
#pragma unroll
            for (int t = 0; t < 9; ++t)
#pragma unroll
                for (int h = 0; h < NHALF; ++h)
                    awc[t * NHALF + h] = *(const short8v*)(
                        wf + ((((size_t)pass * 9 + t) * NHALF + h) * 64 + lane) * 8);
        }

#pragma unroll
        for (int t = 0; t < 9; ++t) {
            const int iy = oy * STRIDE + t / 3 - 1;
            const bool rowok = (unsigned)iy < (unsigned)Hin;
            const int iyc = min(max(iy, 0), Hin - 1);

            short8v bvs[NT];
#pragma unroll
            for (int nt = 0; nt < NT; ++nt) {
                const int ox = x0 + nt * 16 + lp;
                const int ix = ox * STRIDE + t % 3 - 1;
                const bool ok = rowok & ((unsigned)ix < (unsigned)Win);
                const int ixc = min(max(ix, 0), Win - 1);
                short8v bv = *(const short8v*)(inp + ((size_t)iyc * Win + ixc) * 32 + g * 8);
                bvs[nt] = ok ? bv : zero;
            }
#pragma unroll
            for (int h = 0; h < NHALF; ++h) {
                short8v av;
                if constexpr (CACHE_A)
                    av = awc[t * NHALF + h];
                else
                    av = *(const short8v*)(
                        wf + ((((size_t)pass * 9 + t) * NHALF + h) * 64 + lane) * 8);
#pragma unroll
                for (int nt = 0; nt < NT; ++nt)
                    acc[nt][h] = __builtin_amdgcn_mfma_f32_16x16x32_bf16(
                        av, bvs[nt], acc[nt][h], 0, 0, 0);
            }
        }
    }

    const size_t outBase = ((size_t)b * Hout + oy) * Wout;
#pragma unroll
    for (int nt = 0; nt < NT; ++nt) {
        const int p = x0 + nt * 16 + lp;
        short* op = out + (outBase + p) * OCS;
#pragma unroll
        for (int h = 0; h < NHALF; ++h) {
            ushort4 st;
#pragma unroll
            for (int j = 0; j < 4; ++j) {
                const int co = h * 16 + g * 4 + j;
                float v = acc[nt][h][j] + bias[min(co, coutTot - 1)];
                if (LRELU) v = (v >= 0.f) ? v : 0.1f * v;
                ((unsigned short*)&st)[j] = f2bf(v);
            }
            const int co0 = h * 16 + g * 4;
            if (co0 < coutTot)
                *(ushort4*)(op + co0) = st;
        }
    }
}

// ---------------------------------------------------------------------------
// Weight prep: [O][I][3][3] fp32 -> fragment layout bf16.
struct WPArgs {
    const float* src[11];
    int off[11];      // dst offset in shorts
    int npass[11], nhalf[11], O[11];
};

__global__ __launch_bounds__(BDIM)
void wprep_k(WPArgs a, short* __restrict__ wbase)
{
    const int z = blockIdx.z;
    const int n = a.npass[z] * 9 * a.nhalf[z] * 512;
    const int idx = blockIdx.x * BDIM + threadIdx.x;
    if (idx >= n) return;
    const int j = idx & 7;
    const int l = (idx >> 3) & 63;
    int r = idx >> 9;
    const int h = r % a.nhalf[z]; r /= a.nhalf[z];
    const int t = r % 9;
    const int pass = r / 9;
    const int I = a.npass[z] * 32;
    const int cout = h * 16 + (l & 15);
    const int cin  = pass * 32 + (l >> 4) * 8 + j;
    float v = (cout < a.O[z]) ? a.src[z][((size_t)cout * I + cin) * 9 + t] : 0.f;
    wbase[a.off[z] + idx] = (short)f2bf(v);
}

// dcn weights [32o][32i][3][3] -> [tap][half][lane][8] bf16 frags
__global__ __launch_bounds__(BDIM)
void wdp_k(const float* __restrict__ w, short* __restrict__ dst)
{
    const int idx = blockIdx.x * BDIM + threadIdx.x;
    if (idx >= 9 * 2 * 64 * 8) return;
    const int j = idx & 7;
    const int l = (idx >> 3) & 63;
    const int h = (idx >> 9) & 1;
    const int k = idx >> 10;
    const int cout = h * 16 + (l & 15);
    const int cin  = (l >> 4) * 8 + j;
    dst[idx] = (short)f2bf(w[((size_t)cout * 32 + cin) * 9 + k]);
}

// fea NCHW fp32 -> NHWC bf16 (two tensors in one launch via z)
__global__ __launch_bounds__(BDIM)
void cvtnhwc_k(const float* __restrict__ s0, const float* __restrict__ s1,
               short* __restrict__ d0, short* __restrict__ d1, int H, int W)
{
    const float* s = blockIdx.z ? s1 : s0;
    short* d = blockIdx.z ? d1 : d0;
    const int idx = blockIdx.x * BDIM + threadIdx.x;
    if (idx >= 4 * 32 * H * W) return;
    const int c = idx & 31;
    int t = idx >> 5;
    const int x = t % W; t /= W;
    const int y = t % H;
    const int b = t / H;
    d[idx] = (short)f2bf(s[(((size_t)b * 32 + c) * H + y) * W + x]);
}

// Bilinear 2x upsample, NHWC bf16, half-pixel centers, edge clamp.
__global__ __launch_bounds__(BDIM)
void up2b_k(const short* __restrict__ in, short* __restrict__ out,
            int Hin, int Win)
{
    const int Hout = 2 * Hin, Wout = 2 * Win;
    const int idx = blockIdx.x * BDIM + threadIdx.x;
    if (idx >= 4 * Hout * Wout * 4) return;
    const int cg = idx & 3;
    int t = idx >> 2;
    const int x = t % Wout; t /= Wout;
    const int y = t % Hout;
    const int b = t / Hout;

    const float sy = (y + 0.5f) * 0.5f - 0.5f;
    const float sx = (x + 0.5f) * 0.5f - 0.5f;
    const float y0f = floorf(sy), x0f = floorf(sx);
    const float wy = sy - y0f, wx = sx - x0f;
    const int y0 = (int)y0f, x0 = (int)x0f;
    const int y0c = min(max(y0, 0), Hin - 1);
    const int y1c = min(max(y0 + 1, 0), Hin - 1);
    const int x0c = min(max(x0, 0), Win - 1);
    const int x1c = min(max(x0 + 1, 0), Win - 1);

    const short* base = in + (size_t)b * Hin * Win * 32 + cg * 8;
    short8v v00 = *(const short8v*)(base + ((size_t)y0c * Win + x0c) * 32);
    short8v v01 = *(const short8v*)(base + ((size_t)y0c * Win + x1c) * 32);
    short8v v10 = *(const short8v*)(base + ((size_t)y1c * Win + x0c) * 32);
    short8v v11 = *(const short8v*)(base + ((size_t)y1c * Win + x1c) * 32);

    short8v o;
#pragma unroll
    for (int j = 0; j < 8; ++j) {
        float f = (1.f - wy) * ((1.f - wx) * bf2f((unsigned short)v00[j]) +
                                wx * bf2f((unsigned short)v01[j]))
                + wy * ((1.f - wx) * bf2f((unsigned short)v10[j]) +
                        wx * bf2f((unsigned short)v11[j]));
        o[j] = (short)f2bf(f);
    }
    short* op = out + (size_t)b * Hout * Wout * 32 + ((size_t)y * Wout + x) * 32 + cg * 8;
    *(short8v*)op = o;
}

// ---------------------------------------------------------------------------
// Modulated deformable conv (DCNv2) on MFMA. Wave = 16 consecutive x-pixels;
// lane l: pixel (l&15), deformable group (l>>4) -> B-frag k-slot (l>>4)*8+j.
// 2 MFMAs per tap (32 couts, K=32 = all input channels). fp32 planar out.
__global__ __launch_bounds__(BDIM, 4)
void dcnm_k(const short* __restrict__ xb,   // NHWC bf16 [B][H][W][32]
            const short* __restrict__ om,   // NHWC bf16 [B][H][W][112]
            const short* __restrict__ wf,   // [9][2][64][8] bf16 frags
            const float* __restrict__ bias,
            float* __restrict__ out, int H, int W)
{
    const int lane = threadIdx.x & 63;
    const int wid  = blockIdx.x * 4 + (threadIdx.x >> 6);
    const int segs = W / 16;
    const int b = wid / (H * segs);
    int r = wid - b * (H * segs);
    const int y = r / segs;
    const int x = (r - y * segs) * 16 + (lane & 15);
    const int g = lane >> 4;
    const size_t plane = (size_t)H * W;

    f32x4 acc0 = (f32x4){0.f, 0.f, 0.f, 0.f};
    f32x4 acc1 = (f32x4){0.f, 0.f, 0.f, 0.f};

    const short* omb = om + ((size_t)b * plane + (size_t)y * W + x) * 112;
    const short* xbb = xb + (size_t)b * plane * 32 + g * 8;

#pragma unroll
    for (int k = 0; k < 9; ++k) {
        const float offy = bf2f((unsigned short)omb[g * 9 + k]);
        const float offx = bf2f((unsigned short)omb[36 + g * 9 + k]);
        const float ml   = bf2f((unsigned short)omb[72 + g * 9 + k]);
        const float m = 1.f / (1.f + __expf(-ml));

        const float py = offy + (float)y + (float)(k / 3 - 1);
        const float px = offx + (float)x + (float)(k % 3 - 1);
        const float y0f = floorf(py), x0f = floorf(px);
        const int y0 = (int)y0f, x0 = (int)x0f;
        const float wy1 = py - y0f, wx1 = px - x0f;
        const float wy0 = 1.f - wy1, wx0 = 1.f - wx1;

        const bool y0ok = (unsigned)y0 < (unsigned)H;
        const bool y1ok = (unsigned)(y0 + 1) < (unsigned)H;
        const bool x0ok = (unsigned)x0 < (unsigned)W;
        const bool x1ok = (unsigned)(x0 + 1) < (unsigned)W;
        const int y0c = min(max(y0, 0), H - 1);
        const int y1c = min(max(y0 + 1, 0), H - 1);
        const int x0c = min(max(x0, 0), W - 1);
        const int x1c = min(max(x0 + 1, 0), W - 1);

        const float w00 = wy0 * wx0 * ((y0ok && x0ok) ? 1.f : 0.f) * m;
        const float w01 = wy0 * wx1 * ((y0ok && x1ok) ? 1.f : 0.f) * m;
        const float w10 = wy1 * wx0 * ((y1ok && x0ok) ? 1.f : 0.f) * m;
        const float w11 = wy1 * wx1 * ((y1ok && x1ok) ? 1.f : 0.f) * m;

        short8v v00 = *(const short8v*)(xbb + ((size_t)y0c * W + x0c) * 32);
        short8v v01 = *(const short8v*)(xbb + ((size_t)y0c * W + x1c) * 32);
        short8v v10 = *(const short8v*)(xbb + ((size_t)y1c * W + x0c) * 32);
        short8v v11 = *(const short8v*)(xbb + ((size_t)y1c * W + x1c) * 32);

        short8v bv;
#pragma unroll
        for (int j = 0; j < 8; ++j) {
            float s = w00 * bf2f((unsigned short)v00[j])
                    + w01 * bf2f((unsigned short)v01[j])
                    + w10 * bf2f((unsigned short)v10[j])
                    + w11 * bf2f((unsigned short)v11[j]);
            bv[j] = (short)f2bf(s);
        }

        short8v a0 = *(const short8v*)(wf + (((size_t)k * 2 + 0) * 64 + lane) * 8);
        short8v a1 = *(const short8v*)(wf + (((size_t)k * 2 + 1) * 64 + lane) * 8);
        acc0 = __builtin_amdgcn_mfma_f32_16x16x32_bf16(a0, bv, acc0, 0, 0, 0);
        acc1 = __builtin_amdgcn_mfma_f32_16x16x32_bf16(a1, bv, acc1, 0, 0, 0);
    }

    float* op = out + (size_t)b * 32 * plane + (size_t)y * W + x;
#pragma unroll
    for (int j = 0; j < 4; ++j) {
        const int co0 = g * 4 + j;
        const int co1 = 16 + g * 4 + j;
        op[(size_t)co0 * plane] = acc0[j] + bias[co0];
        op[(size_t)co1 * plane] = acc1[j] + bias[co1];
    }
}

// ---------------------------------------------------------------------------

extern "C" void kernel_launch(void* const* d_in, const int* in_sizes, int n_in,
                              void* d_out, int out_size, void* d_ws, size_t ws_size,
                              hipStream_t stream)
{
    const float* fea1  = (const float*)d_in[0];
    const float* fea2  = (const float*)d_in[1];
    const float* w1_1  = (const float*)d_in[2];  const float* b1_1 = (const float*)d_in[3];
    const float* w2_1  = (const float*)d_in[4];  const float* b2_1 = (const float*)d_in[5];
    const float* w3_1  = (const float*)d_in[6];  const float* b3_1 = (const float*)d_in[7];
    const float* w4_1  = (const float*)d_in[8];  const float* b4_1 = (const float*)d_in[9];
    const float* w6_1  = (const float*)d_in[10]; const float* b6_1 = (const float*)d_in[11];
    const float* w7_1  = (const float*)d_in[12]; const float* b7_1 = (const float*)d_in[13];
    const float* w1_2  = (const float*)d_in[14]; const float* b1_2 = (const float*)d_in[15];
    const float* w2_2  = (const float*)d_in[16]; const float* b2_2 = (const float*)d_in[17];
    const float* w3_2  = (const float*)d_in[18]; const float* b3_2 = (const float*)d_in[19];
    const float* w4_2  = (const float*)d_in[20]; const float* b4_2 = (const float*)d_in[21];
    const float* w_om  = (const float*)d_in[22]; const float* b_om = (const float*)d_in[23];
    const float* w_dcn = (const float*)d_in[24]; const float* b_dcn= (const float*)d_in[25];

    const int H = 192, W = 192;
    char* ws = (char*)d_ws;

    // byte offsets; fea2b stays live to the end (dcnm samples it)
    short* fea1b = (short*)(ws + 0);          // bf16 NHWC 192  (9.44 MB)
    short* fea2b = (short*)(ws + 9437184);    // LIVE TO END
    short* bufA  = (short*)(ws + 18874368);   // off      192
    short* bufB  = (short*)(ws + 28311552);   // off1     192 (lives to conv3_2)
    short* bufC  = (short*)(ws + 0);          // off2a    96  (fea1b dead)
    short* bufD  = (short*)(ws + 2359296);    // off2     96
    short* bufE  = (short*)(ws + 4718592);    // off3a    48
    short* bufF  = (short*)(ws + 5308416);    // off3     48
    short* bufG  = (short*)(ws + 5898240);    // up96     96
    short* bufH  = (short*)(ws + 0);          // conv1_2 out 96 (bufC dead)
    short* bufI  = (short*)(ws + 4718592);    // conv2_2 out 96 (E/F dead)
    short* bufJ  = (short*)(ws + 37748736);   // up192 (om slot, written later)
    short* bufK  = (short*)(ws + 18874368);   // conv3_2 out (bufA dead)
    short* bufL  = (short*)(ws + 0);          // base_offset 192 (H/D/I dead)
    short* om    = (short*)(ws + 37748736);   // NHWC bf16 stride 112 (33.0 MB)
    short* wfrag = (short*)(ws + 70778880);   // conv weight frags (304 KB)
    short* wfdcn = (short*)(ws + 71083008);   // dcn weight frags (18.4 KB)

    const int WOFF[11] = {0, 18432, 27648, 36864, 46080, 55296,
                          64512, 82944, 92160, 110592, 119808};

    dim3 blk(BDIM, 1, 1);

    // 0. weight prep + input conversions
    {
        WPArgs a;
        const float* srcs[11] = {w1_1, w2_1, w3_1, w4_1, w6_1, w7_1,
                                 w1_2, w2_2, w3_2, w4_2, w_om};
        const int NP[11] = {2,1,1,1,1,1,2,1,2,1,1};
        const int NH[11] = {2,2,2,2,2,2,2,2,2,2,7};
        const int Os[11] = {32,32,32,32,32,32,32,32,32,32,108};
        for (int i = 0; i < 11; ++i) {
            a.src[i] = srcs[i]; a.off[i] = WOFF[i];
            a.npass[i] = NP[i]; a.nhalf[i] = NH[i]; a.O[i] = Os[i];
        }
        wprep_k<<<dim3(126, 1, 11), blk, 0, stream>>>(a, wfrag);
        cvtnhwc_k<<<dim3(18432, 1, 2), blk, 0, stream>>>(fea1, fea2, fea1b, fea2b, H, W);
        wdp_k<<<dim3(36), blk, 0, stream>>>(w_dcn, wfdcn);
    }

    // 1. off = lrelu(conv1_1(cat(fea1, fea2)))           192
    convm_k<2,2,2,1,true><<<dim3(1152), blk, 0, stream>>>(
        fea1b, fea2b, wfrag + WOFF[0], b1_1, bufA, 192,192,192,192, 32, 32);
    // 2. off1 = lrelu(conv2_1(off))                      192
    convm_k<1,2,2,1,true><<<dim3(1152), blk, 0, stream>>>(
        bufA, nullptr, wfrag + WOFF[1], b2_1, bufB, 192,192,192,192, 32, 32);
    // 3. off2a = lrelu(conv3_1(off1, s2))                96
    convm_k<1,2,1,2,true><<<dim3(576), blk, 0, stream>>>(
        bufB, nullptr, wfrag + WOFF[2], b3_1, bufC, 192,192,96,96, 32, 32);
    // 4. off2 = lrelu(conv4_1(off2a))                    96
    convm_k<1,2,1,1,true><<<dim3(576), blk, 0, stream>>>(
        bufC, nullptr, wfrag + WOFF[3], b4_1, bufD, 96,96,96,96, 32, 32);
    // 5. off3a = lrelu(conv6_1(off2, s2))                48
    convm_k<1,2,1,2,true><<<dim3(144), blk, 0, stream>>>(
        bufD, nullptr, wfrag + WOFF[4], b6_1, bufE, 96,96,48,48, 32, 32);
    // 6. off3 = lrelu(conv7_1(off3a))                    48
    convm_k<1,2,1,1,true><<<dim3(144), blk, 0, stream>>>(
        bufE, nullptr, wfrag + WOFF[5], b7_1, bufF, 48,48,48,48, 32, 32);
    // 7. up96 = up2(off3)
    up2b_k<<<dim3(576), blk, 0, stream>>>(bufF, bufG, 48, 48);
    // 8. t = lrelu(conv1_2(cat(up96, off2)))             96
    convm_k<2,2,1,1,true><<<dim3(576), blk, 0, stream>>>(
        bufG, bufD, wfrag + WOFF[6], b1_2, bufH, 96,96,96,96, 32, 32);
    // 9. t2 = lrelu(conv2_2(t))                          96
    convm_k<1,2,1,1,true><<<dim3(576), blk, 0, stream>>>(
        bufH, nullptr, wfrag + WOFF[7], b2_2, bufI, 96,96,96,96, 32, 32);
    // 10. up192 = up2(t2)
    up2b_k<<<dim3(2304), blk, 0, stream>>>(bufI, bufJ, 96, 96);
    // 11. off = lrelu(conv3_2(cat(up192, off1)))         192
    convm_k<2,2,2,1,true><<<dim3(1152), blk, 0, stream>>>(
        bufJ, bufB, wfrag + WOFF[8], b3_2, bufK, 192,192,192,192, 32, 32);
    // 12. base_offset = conv4_2(off)    (no lrelu)       192
    convm_k<1,2,2,1,false><<<dim3(1152), blk, 0, stream>>>(
        bufK, nullptr, wfrag + WOFF[9], b4_2, bufL, 192,192,192,192, 32, 32);
    // 13. om = conv_om(base_offset)  32 -> 108 (pad 112) 192
    convm_k<1,7,2,1,false><<<dim3(1152), blk, 0, stream>>>(
        bufL, nullptr, wfrag + WOFF[10], b_om, om, 192,192,192,192, 112, 108);
    // 14. out = deform_conv(fea2, om)
    dcnm_k<<<dim3(2304), blk, 0, stream>>>(
        fea2b, om, wfdcn, b_dcn, (float*)d_out, H, W);
}